// Round 15
// baseline (232.887 us; speedup 1.0000x reference)
//
#include <hip/hip_runtime.h>
#include <hip/hip_bf16.h>

#define NN 50000
#define EE 600000
#define FH 128
#define GG 128
#define CC 16
#define NBLK ((NN + 255) / 256)   // 196 node blocks (CSR barrier group)
#define GEMMB 782                 // 64-row gemm tiles
#define PP 192                    // edge chunks (hist/fill blocks)
#define EPP 3125                  // edges per chunk (192*3125 == 600000)

typedef __attribute__((ext_vector_type(8))) short bf16x8;
typedef __attribute__((ext_vector_type(4))) float f32x4;

static __device__ __forceinline__ unsigned short f2bf(float f) {
    union { float f; unsigned int u; } v; v.f = f;
    unsigned int r = v.u + 0x7fffu + ((v.u >> 16) & 1u);   // RNE
    return (unsigned short)(r >> 16);
}
static __device__ __forceinline__ float bf2f(unsigned short h) {
    union { unsigned int u; float f; } v; v.u = ((unsigned int)h) << 16;
    return v.f;
}
// async global->LDS, 16B per lane; lds base must be wave-uniform
static __device__ __forceinline__ void ld16(const void* g, void* l) {
    __builtin_amdgcn_global_load_lds((const __attribute__((address_space(1))) void*)g,
                                     (__attribute__((address_space(3))) void*)l, 16, 0, 0);
}
// grid barrier for the first NBLK blocks (all guaranteed co-resident:
// 50KB LDS/256thr -> >=3 blocks/CU -> 768 slots >> 196 spinners; gemm blocks
// never spin so freed slots always admit remaining spinners -> no deadlock).
static __device__ __forceinline__ void gridbar(int* c, int idx, int nb) {
    __threadfence();                 // every thread releases its writes
    __syncthreads();
    if (threadIdx.x == 0) {
        atomicAdd(&c[idx], 1);
        while (__hip_atomic_load(&c[idx], __ATOMIC_ACQUIRE,
                                 __HIP_MEMORY_SCOPE_AGENT) < nb)
            __builtin_amdgcn_s_sleep(2);
    }
    __syncthreads();
}

// ---- prep (512 thr): W transpose | gstart | x->bf16 | per-chunk dst hist
//      | zero grid-barrier counters ----
__global__ __launch_bounds__(512) void k_prep(const float* __restrict__ x,
                                              unsigned short* __restrict__ XB,
                                              const float* __restrict__ W1,
                                              const float* __restrict__ W2,
                                              unsigned short* __restrict__ WT1,
                                              unsigned short* __restrict__ WT2,
                                              const int* __restrict__ batch,
                                              int* __restrict__ gstart,
                                              const int* __restrict__ dst,
                                              unsigned int* __restrict__ histw,
                                              int* __restrict__ barc) {
    __shared__ unsigned int lh[12500];         // only hist blocks use it
    const int b = blockIdx.x, t = threadIdx.x;
    if (b < PP) {                              // hist chunk b
        for (int w = t; w < 12500; w += 512) lh[w] = 0u;
        __syncthreads();
        const int e1 = (b + 1) * EPP;
        for (int e = b * EPP + t; e < e1; e += 512) {
            int d = dst[e];
            atomicAdd(&lh[d >> 2], 1u << (8 * (d & 3)));
        }
        __syncthreads();
        for (int w = t; w < 12500; w += 512) histw[(size_t)b * 12500 + w] = lh[w];
    } else if (b < PP + 64) {
        int o = (b - PP) * 512 + t;            // 0..32767
        const float* W = (o < 16384) ? W1 : W2;
        unsigned short* WT = (o < 16384) ? WT1 : WT2;
        int oo = o & 16383;
        int c = oo >> 7, k = oo & 127;
        WT[oo] = f2bf(W[k * 128 + c]);
    } else if (b == PP + 64) {
        if (t <= GG) {
            int lo = 0, hi = NN;
            while (lo < hi) {
                int mid = (lo + hi) >> 1;
                if (batch[mid] < t) lo = mid + 1; else hi = mid;
            }
            gstart[t] = lo;
        }
        if (t >= 200 && t < 204) barc[t - 200] = 0;   // reset barriers each call
    } else {
        int o = (b - PP - 65) * 512 + t;       // 8 floats each, guard 800000
        if (o < 800000) {
            const float4* xp = (const float4*)x + (size_t)o * 2;
            float4 f0 = xp[0], f1 = xp[1];
            uint4 v;
            v.x = (unsigned)f2bf(f0.x) | ((unsigned)f2bf(f0.y) << 16);
            v.y = (unsigned)f2bf(f0.z) | ((unsigned)f2bf(f0.w) << 16);
            v.z = (unsigned)f2bf(f1.x) | ((unsigned)f2bf(f1.y) << 16);
            v.w = (unsigned)f2bf(f1.z) | ((unsigned)f2bf(f1.w) << 16);
            ((uint4*)XB)[o] = v;
        }
    }
}
#define PREPB (PP + 65 + 1563)   // 192 hist + 64 W + 1 gstart + 1563 conv

// ---- mega: blocks [0,NBLK) run CSR chain {scanA|BAR|scanBC|BAR|fill|BAR|
//      degsum}; blocks [NBLK, NBLK+GEMMB) run layer-1 GEMM concurrently ----
__global__ __launch_bounds__(256, 3) void k_mega(const unsigned char* __restrict__ hist8,
                                                 unsigned short* __restrict__ cb16,
                                                 int* __restrict__ cnt,
                                                 int* __restrict__ bs,
                                                 int* __restrict__ rowptr,
                                                 const int* __restrict__ src,
                                                 const int* __restrict__ dst,
                                                 const float* __restrict__ ew,
                                                 int2* __restrict__ bucket,
                                                 float* __restrict__ dinv,
                                                 int* __restrict__ barc,
                                                 const unsigned short* __restrict__ Xin,
                                                 const unsigned short* __restrict__ Wt,
                                                 unsigned short* __restrict__ Y,
                                                 int nrows) {
    __shared__ char smem[50176];               // fill: 50000B hist | gemm: 49152B tiles
    const int t = threadIdx.x;

    if (blockIdx.x < NBLK) {
        const int b = blockIdx.x;
        // ---- phase 1: scanA ----
        {
            int i = b * 256 + t;
            int run = 0;
            if (i < NN) {
                for (int p = 0; p < PP; p += 32) {
                    unsigned char hh[32];
#pragma unroll
                    for (int q = 0; q < 32; q++) hh[q] = hist8[(size_t)(p + q) * 50000 + i];
#pragma unroll
                    for (int q = 0; q < 32; q++) {
                        cb16[(size_t)(p + q) * 50000 + i] = (unsigned short)run;
                        run += hh[q];
                    }
                }
                cnt[i] = run;
            }
            int v = run;
#pragma unroll
            for (int o = 32; o >= 1; o >>= 1) v += __shfl_down(v, o, 64);
            int* ws = (int*)smem;
            if ((t & 63) == 0) ws[t >> 6] = v;
            __syncthreads();
            if (t == 0) bs[b] = ws[0] + ws[1] + ws[2] + ws[3];
        }
        gridbar(barc, 0, NBLK);
        // ---- phase 2: scanBC ----
        {
            int* sb = (int*)smem;
            int* sc = sb + 256;
            const volatile int* vbs = (const volatile int*)bs;
            int vb = (t < NBLK) ? vbs[t] : 0;
            sb[t] = vb;
            __syncthreads();
            for (int off = 1; off < 256; off <<= 1) {
                int add = (t >= off) ? sb[t - off] : 0;
                __syncthreads();
                sb[t] += add;
                __syncthreads();
            }
            const int boff = (b > 0) ? sb[b - 1] : 0;
            const int i = b * 256 + t;
            int v = (i < NN) ? ((const volatile int*)cnt)[i] : 0;
            sc[t] = v;
            __syncthreads();
            for (int off = 1; off < 256; off <<= 1) {
                int add = (t >= off) ? sc[t - off] : 0;
                __syncthreads();
                sc[t] += add;
                __syncthreads();
            }
            int excl = sc[t] - v + boff;
            if (i < NN) rowptr[i] = excl;
            if (i == 0) rowptr[NN] = EE;
        }
        gridbar(barc, 1, NBLK);
        // ---- phase 3: fill (blocks < PP) ----
        {
            unsigned int* lh = (unsigned int*)smem;
            for (int w = t; w < 12500; w += 256) lh[w] = 0u;
            __syncthreads();
            if (b < PP) {
                const volatile int* vrp = (const volatile int*)rowptr;
                const volatile unsigned short* vcb = (const volatile unsigned short*)cb16;
                const int e1 = (b + 1) * EPP;
                for (int e = b * EPP + t; e < e1; e += 256) {
                    int d = dst[e];
                    int sh = 8 * (d & 3);
                    unsigned int old = atomicAdd(&lh[d >> 2], 1u << sh);
                    int lr = (int)((old >> sh) & 0xffu);
                    int pos = vrp[d] + (int)vcb[(size_t)b * 50000 + d] + lr;
                    bucket[pos] = make_int2(src[e], __float_as_int(ew[e]));
                }
            }
        }
        gridbar(barc, 2, NBLK);
        // ---- phase 4: degsum ----
        {
            int n = b * 256 + t;
            if (n < NN) {
                const volatile int* vrp = (const volatile int*)rowptr;
                const volatile int* vbk = (const volatile int*)bucket;
                float s = 0.f;
                const int e1 = vrp[n + 1];
                for (int e = vrp[n]; e < e1; e++) s += __int_as_float(vbk[2 * e + 1]);
                dinv[n] = rsqrtf(s + 1.0f);
            }
        }
        return;
    }

    // ---- gemm part (blocks NBLK..NBLK+GEMMB) ----
    const int bg = blockIdx.x - NBLK;
    const int lane = t & 63, w = t >> 6;
    const int r0 = bg * 64;
    const char* Wb = (const char*)Wt;
    const char* Xb = (const char*)Xin;

#pragma unroll
    for (int j = 0; j < 12; j++) {
        const int base = (j * 4 + w) * 64;     // chunk index of lane 0 (uniform)
        const int ci = base + lane;            // 0..3071
        char* ldst = smem + (size_t)base * 16;
        if (base < 2048) {
            int row = ci >> 4, slot = ci & 15;
            ld16(Wb + row * 256 + ((slot ^ (row & 7)) * 16), ldst);
        } else {
            int xci = ci - 2048;
            int row = xci >> 4, slot = xci & 15;
            ld16(Xb + (size_t)(r0 + row) * 256 + ((slot ^ (row & 7)) * 16), ldst);
        }
    }
    __syncthreads();

    const int wr = (w >> 1) * 32, wc = (w & 1) * 64;
    const int lr = lane & 15, lg = lane >> 4;
    f32x4 acc[2][4];
#pragma unroll
    for (int a = 0; a < 2; a++)
#pragma unroll
        for (int c = 0; c < 4; c++) acc[a][c] = (f32x4){0.f, 0.f, 0.f, 0.f};

#pragma unroll
    for (int tt = 0; tt < 4; tt++) {
        const int kb = tt * 64 + lg * 16;
        bf16x8 af[2], bf[4];
#pragma unroll
        for (int i = 0; i < 2; i++) {
            int ar = wr + i * 16 + lr;
            af[i] = *(const bf16x8*)(smem + 32768 + ar * 256 + (kb ^ ((ar & 7) << 4)));
        }
#pragma unroll
        for (int i = 0; i < 4; i++) {
            int bc = wc + i * 16 + lr;
            bf[i] = *(const bf16x8*)(smem + bc * 256 + (kb ^ ((bc & 7) << 4)));
        }
#pragma unroll
        for (int fr = 0; fr < 2; fr++)
#pragma unroll
            for (int fc = 0; fc < 4; fc++)
                acc[fr][fc] = __builtin_amdgcn_mfma_f32_16x16x32_bf16(af[fr], bf[fc], acc[fr][fc], 0, 0, 0);
    }

    __syncthreads();
#pragma unroll
    for (int fr = 0; fr < 2; fr++)
#pragma unroll
        for (int fc = 0; fc < 4; fc++)
#pragma unroll
            for (int j = 0; j < 4; j++) {
                int row = wr + fr * 16 + lg * 4 + j;
                int col = wc + fc * 16 + lr;
                *(unsigned short*)(smem + row * 272 + col * 2) = f2bf(acc[fr][fc][j]);
            }
    __syncthreads();
#pragma unroll
    for (int j = 0; j < 4; j++) {
        int ci = t + 256 * j;
        int row = ci >> 4, slot = ci & 15;
        int grow = r0 + row;
        if (grow < nrows)
            ((uint4*)(Y + (size_t)grow * 128))[slot] = *(const uint4*)(smem + row * 272 + slot * 16);
    }
}

// ---- MFMA GEMM (bf16 in, bf16 out), async global_load_lds staging ----
__global__ __launch_bounds__(256, 3) void k_gemm(const unsigned short* __restrict__ Xin,
                                                 const unsigned short* __restrict__ Wt,
                                                 unsigned short* __restrict__ Y,
                                                 int nrows) {
    __shared__ char smem[49152];
    const int tid = threadIdx.x;
    const int lane = tid & 63, w = tid >> 6;
    const int r0 = blockIdx.x * 64;
    const char* Wb = (const char*)Wt;
    const char* Xb = (const char*)Xin;

#pragma unroll
    for (int j = 0; j < 12; j++) {
        const int base = (j * 4 + w) * 64;
        const int ci = base + lane;
        char* ldst = smem + (size_t)base * 16;
        if (base < 2048) {
            int row = ci >> 4, slot = ci & 15;
            ld16(Wb + row * 256 + ((slot ^ (row & 7)) * 16), ldst);
        } else {
            int xci = ci - 2048;
            int row = xci >> 4, slot = xci & 15;
            ld16(Xb + (size_t)(r0 + row) * 256 + ((slot ^ (row & 7)) * 16), ldst);
        }
    }
    __syncthreads();

    const int wr = (w >> 1) * 32, wc = (w & 1) * 64;
    const int lr = lane & 15, lg = lane >> 4;
    f32x4 acc[2][4];
#pragma unroll
    for (int a = 0; a < 2; a++)
#pragma unroll
        for (int c = 0; c < 4; c++) acc[a][c] = (f32x4){0.f, 0.f, 0.f, 0.f};

#pragma unroll
    for (int t = 0; t < 4; t++) {
        const int kb = t * 64 + lg * 16;
        bf16x8 af[2], bf[4];
#pragma unroll
        for (int i = 0; i < 2; i++) {
            int ar = wr + i * 16 + lr;
            af[i] = *(const bf16x8*)(smem + 32768 + ar * 256 + (kb ^ ((ar & 7) << 4)));
        }
#pragma unroll
        for (int i = 0; i < 4; i++) {
            int bc = wc + i * 16 + lr;
            bf[i] = *(const bf16x8*)(smem + bc * 256 + (kb ^ ((bc & 7) << 4)));
        }
#pragma unroll
        for (int fr = 0; fr < 2; fr++)
#pragma unroll
            for (int fc = 0; fc < 4; fc++)
                acc[fr][fc] = __builtin_amdgcn_mfma_f32_16x16x32_bf16(af[fr], bf[fc], acc[fr][fc], 0, 0, 0);
    }

    __syncthreads();
#pragma unroll
    for (int fr = 0; fr < 2; fr++)
#pragma unroll
        for (int fc = 0; fc < 4; fc++)
#pragma unroll
            for (int j = 0; j < 4; j++) {
                int row = wr + fr * 16 + lg * 4 + j;
                int col = wc + fc * 16 + lr;
                *(unsigned short*)(smem + row * 272 + col * 2) = f2bf(acc[fr][fc][j]);
            }
    __syncthreads();
#pragma unroll
    for (int j = 0; j < 4; j++) {
        int ci = tid + 256 * j;
        int row = ci >> 4, slot = ci & 15;
        int grow = r0 + row;
        if (grow < nrows)
            ((uint4*)(Y + (size_t)grow * 128))[slot] = *(const uint4*)(smem + row * 272 + slot * 16);
    }
}

// ---- gather-aggregate + self-loop + bias + relu (bf16 in/out) ----
// One wave per node; 4 edge-groups x 4-deep unroll = 16 row loads in flight.
__global__ __launch_bounds__(256) void k_gather(const unsigned short* __restrict__ XW,
                                                const int* __restrict__ rowptr,
                                                const int2* __restrict__ bucket,
                                                const float* __restrict__ dinv,
                                                const float* __restrict__ b,
                                                unsigned short* __restrict__ H) {
    const int wv = threadIdx.x >> 6, lane = threadIdx.x & 63;
    const int n = blockIdx.x * 4 + wv;
    if (n >= NN) return;
    const int eg = lane >> 4;        // edge group 0..3
    const int fl = lane & 15;        // 16B feature slot
    const float di = dinv[n];
    const float sl = di * di;
    uint4 su = ((const uint4*)(XW + (size_t)n * 128))[fl];
    float acc[8];
#pragma unroll
    for (int q = 0; q < 8; q++) acc[q] = 0.f;
    const int e0 = rowptr[n], e1 = rowptr[n + 1];
    int e = e0 + eg;
    for (; e + 12 < e1; e += 16) {   // 4 edges per group per iter
        int2 p0 = bucket[e];
        int2 p1 = bucket[e + 4];
        int2 p2 = bucket[e + 8];
        int2 p3 = bucket[e + 12];
        float nm0 = dinv[p0.x] * __int_as_float(p0.y) * di;
        float nm1 = dinv[p1.x] * __int_as_float(p1.y) * di;
        float nm2 = dinv[p2.x] * __int_as_float(p2.y) * di;
        float nm3 = dinv[p3.x] * __int_as_float(p3.y) * di;
        uint4 v0 = ((const uint4*)(XW + (size_t)p0.x * 128))[fl];
        uint4 v1 = ((const uint4*)(XW + (size_t)p1.x * 128))[fl];
        uint4 v2 = ((const uint4*)(XW + (size_t)p2.x * 128))[fl];
        uint4 v3 = ((const uint4*)(XW + (size_t)p3.x * 128))[fl];
        unsigned int u0[4] = {v0.x, v0.y, v0.z, v0.w};
        unsigned int u1[4] = {v1.x, v1.y, v1.z, v1.w};
        unsigned int u2[4] = {v2.x, v2.y, v2.z, v2.w};
        unsigned int u3[4] = {v3.x, v3.y, v3.z, v3.w};
#pragma unroll
        for (int q = 0; q < 4; q++) {
            acc[2 * q]     = fmaf(__uint_as_float(u0[q] << 16), nm0, acc[2 * q]);
            acc[2 * q + 1] = fmaf(__uint_as_float(u0[q] & 0xffff0000u), nm0, acc[2 * q + 1]);
            acc[2 * q]     = fmaf(__uint_as_float(u1[q] << 16), nm1, acc[2 * q]);
            acc[2 * q + 1] = fmaf(__uint_as_float(u1[q] & 0xffff0000u), nm1, acc[2 * q + 1]);
            acc[2 * q]     = fmaf(__uint_as_float(u2[q] << 16), nm2, acc[2 * q]);
            acc[2 * q + 1] = fmaf(__uint_as_float(u2[q] & 0xffff0000u), nm2, acc[2 * q + 1]);
            acc[2 * q]     = fmaf(__uint_as_float(u3[q] << 16), nm3, acc[2 * q]);
            acc[2 * q + 1] = fmaf(__uint_as_float(u3[q] & 0xffff0000u), nm3, acc[2 * q + 1]);
        }
    }
    for (; e < e1; e += 4) {         // tail, stride 4 per group
        int2 p = bucket[e];
        float nm = dinv[p.x] * __int_as_float(p.y) * di;
        uint4 v = ((const uint4*)(XW + (size_t)p.x * 128))[fl];
        unsigned int uu[4] = {v.x, v.y, v.z, v.w};
#pragma unroll
        for (int q = 0; q < 4; q++) {
            acc[2 * q]     = fmaf(__uint_as_float(uu[q] << 16), nm, acc[2 * q]);
            acc[2 * q + 1] = fmaf(__uint_as_float(uu[q] & 0xffff0000u), nm, acc[2 * q + 1]);
        }
    }
#pragma unroll
    for (int q = 0; q < 8; q++) {
        acc[q] += __shfl_xor(acc[q], 16);
        acc[q] += __shfl_xor(acc[q], 32);
    }
    if (eg == 0) {
        unsigned int us[4] = {su.x, su.y, su.z, su.w};
        float4 b0 = ((const float4*)b)[fl * 2];
        float4 b1 = ((const float4*)b)[fl * 2 + 1];
        float bb[8] = {b0.x, b0.y, b0.z, b0.w, b1.x, b1.y, b1.z, b1.w};
        float r[8];
#pragma unroll
        for (int q = 0; q < 4; q++) {
            r[2 * q]     = fmaxf(fmaf(__uint_as_float(us[q] << 16), sl, acc[2 * q]) + bb[2 * q], 0.f);
            r[2 * q + 1] = fmaxf(fmaf(__uint_as_float(us[q] & 0xffff0000u), sl, acc[2 * q + 1]) + bb[2 * q + 1], 0.f);
        }
        uint4 o;
        o.x = (unsigned)f2bf(r[0]) | ((unsigned)f2bf(r[1]) << 16);
        o.y = (unsigned)f2bf(r[2]) | ((unsigned)f2bf(r[3]) << 16);
        o.z = (unsigned)f2bf(r[4]) | ((unsigned)f2bf(r[5]) << 16);
        o.w = (unsigned)f2bf(r[6]) | ((unsigned)f2bf(r[7]) << 16);
        ((uint4*)(H + (size_t)n * 128))[fl] = o;
    }
}

// ---- fused pooling + head: one 512-thread block per graph, no atomics ----
__global__ __launch_bounds__(512) void k_poolhead(const unsigned short* __restrict__ H,
                                                  const int* __restrict__ gstart,
                                                  const float* __restrict__ linW,
                                                  const float* __restrict__ linb,
                                                  float* __restrict__ out) {
    __shared__ float lmx[1024], lsm[1024];
    __shared__ float mxf[128], mnf[128];
    const int g = blockIdx.x, t = threadIdx.x;
    const int slice = t >> 6;
    const int fp = t & 63;
    const int n0 = gstart[g], n1 = gstart[g + 1];
    float mx0 = 0.f, mx1 = 0.f, sm0 = 0.f, sm1 = 0.f;   // h >= 0 post-relu
    for (int n = n0 + slice; n < n1; n += 8) {
        unsigned int u = *(const unsigned int*)(H + (size_t)n * 128 + fp * 2);
        float v0 = bf2f((unsigned short)(u & 0xffffu));
        float v1 = bf2f((unsigned short)(u >> 16));
        mx0 = fmaxf(mx0, v0); mx1 = fmaxf(mx1, v1);
        sm0 += v0; sm1 += v1;
    }
    lmx[slice * 128 + fp * 2] = mx0; lmx[slice * 128 + fp * 2 + 1] = mx1;
    lsm[slice * 128 + fp * 2] = sm0; lsm[slice * 128 + fp * 2 + 1] = sm1;
    __syncthreads();
    if (t < 128) {
        float m = 0.f, s = 0.f;
#pragma unroll
        for (int q = 0; q < 8; q++) {
            m = fmaxf(m, lmx[q * 128 + t]);
            s += lsm[q * 128 + t];
        }
        mxf[t] = m;
        mnf[t] = s / fmaxf((float)(n1 - n0), 1.0f);
    }
    __syncthreads();
    if (t < CC) {
        float z = linb[t];
        for (int f = 0; f < 128; f++) {
            z = fmaf(mxf[f], linW[f * CC + t], z);
            z = fmaf(mnf[f], linW[(128 + f) * CC + t], z);
        }
        float m = z;
        for (int o = 8; o >= 1; o >>= 1) m = fmaxf(m, __shfl_xor(m, o, 16));
        float ex = expf(z - m), s = ex;
        for (int o = 8; o >= 1; o >>= 1) s += __shfl_xor(s, o, 16);
        out[g * CC + t] = z - m - logf(s);
    }
}

extern "C" void kernel_launch(void* const* d_in, const int* in_sizes, int n_in,
                              void* d_out, int out_size, void* d_ws, size_t ws_size,
                              hipStream_t stream) {
    const float* x    = (const float*)d_in[0];
    const int*   ei   = (const int*)d_in[1];
    const float* ew   = (const float*)d_in[2];
    const int*   batch= (const int*)d_in[3];
    const float* W1   = (const float*)d_in[4];
    const float* b1   = (const float*)d_in[5];
    const float* W2   = (const float*)d_in[6];
    const float* b2   = (const float*)d_in[7];
    const float* linW = (const float*)d_in[8];
    const float* linb = (const float*)d_in[9];
    float* out = (float*)d_out;

    // workspace layout: 16B-aligned buffers first
    unsigned short* YB = (unsigned short*)d_ws;              // [N,128] bf16 gemm out
    unsigned short* HB = YB + (size_t)NN * 128;              // [N,128] bf16 gather out
    unsigned short* XB = HB + (size_t)NN * 128;              // [N,128] bf16 input / h2
    unsigned short* WT1 = XB + (size_t)NN * 128;             // [128*128]
    unsigned short* WT2 = WT1 + 128 * 128;                   // [128*128]
    int2*  BUCKET = (int2*)(WT2 + 128 * 128);                // [E] (src, ew)
    float* DINV   = (float*)(BUCKET + EE);                   // [N]
    int*   ROWPTR = (int*)(DINV + NN);                       // [N+1]
    int*   CNT    = ROWPTR + NN + 1;                         // [N]
    int*   GSTART = CNT + NN;                                // [G+1]
    int*   BS     = GSTART + GG + 1;                         // [NBLK]
    int*   BARC   = BS + NBLK;                               // [4] grid-barrier counters
    unsigned int* HISTW = (unsigned int*)(BARC + 4);         // [PP][12500] u8x4
    unsigned short* CB16 = (unsigned short*)(HISTW + (size_t)PP * 12500); // [PP][50000]

    const int* src = ei;
    const int* dst = ei + EE;

    // prep: hist | W transpose | gstart | x->bf16 | zero barrier counters
    k_prep<<<PREPB, 512, 0, stream>>>(x, XB, W1, W2, WT1, WT2, batch, GSTART, dst, HISTW, BARC);

    // mega: CSR chain (196 barrier-synced blocks) + layer-1 GEMM (782 blocks)
    k_mega<<<NBLK + GEMMB, 256, 0, stream>>>((const unsigned char*)HISTW, CB16, CNT, BS,
                                             ROWPTR, src, dst, ew, BUCKET, DINV, BARC,
                                             XB, WT1, YB, NN);

    // layer 1 aggregate
    k_gather<<<(NN + 3) / 4, 256, 0, stream>>>(YB, ROWPTR, BUCKET, DINV, b1, HB);

    // layer 2
    k_gemm<<<GEMMB, 256, 0, stream>>>(HB, WT2, YB, NN);
    k_gather<<<(NN + 3) / 4, 256, 0, stream>>>(YB, ROWPTR, BUCKET, DINV, b2, XB);

    // pooling + head (one block per graph)
    k_poolhead<<<GG, 512, 0, stream>>>(XB, GSTART, linW, linb, out);
}

// Round 17
// 162.936 us; speedup vs baseline: 1.4293x; 1.4293x over previous
//
#include <hip/hip_runtime.h>
#include <hip/hip_bf16.h>

#define NN 50000
#define EE 600000
#define FH 128
#define GG 128
#define CC 16
#define NBLK ((NN + 255) / 256)   // 196 node blocks
#define GEMMB 782                 // 64-row gemm tiles
#define PP 192                    // edge chunks (hist/fill blocks)
#define EPP 3125                  // edges per chunk (192*3125 == 600000)

typedef __attribute__((ext_vector_type(8))) short bf16x8;
typedef __attribute__((ext_vector_type(4))) float f32x4;

static __device__ __forceinline__ unsigned short f2bf(float f) {
    union { float f; unsigned int u; } v; v.f = f;
    unsigned int r = v.u + 0x7fffu + ((v.u >> 16) & 1u);   // RNE
    return (unsigned short)(r >> 16);
}
static __device__ __forceinline__ float bf2f(unsigned short h) {
    union { unsigned int u; float f; } v; v.u = ((unsigned int)h) << 16;
    return v.f;
}
// async global->LDS, 16B per lane; lds base must be wave-uniform
static __device__ __forceinline__ void ld16(const void* g, void* l) {
    __builtin_amdgcn_global_load_lds((const __attribute__((address_space(1))) void*)g,
                                     (__attribute__((address_space(3))) void*)l, 16, 0, 0);
}
// nontemporal 8B bucket load: lo 32b = src index, hi 32b = ew bits
static __device__ __forceinline__ void ntbucket(const long long* p, int& s, float& w) {
    long long v = __builtin_nontemporal_load(p);
    s = (int)(v & 0xffffffffLL);
    w = __uint_as_float((unsigned int)((unsigned long long)v >> 32));
}

// ---- prep (512 thr): W transpose | gstart | x->bf16 | per-chunk dst hist ----
__global__ __launch_bounds__(512) void k_prep(const float* __restrict__ x,
                                              unsigned short* __restrict__ XB,
                                              const float* __restrict__ W1,
                                              const float* __restrict__ W2,
                                              unsigned short* __restrict__ WT1,
                                              unsigned short* __restrict__ WT2,
                                              const int* __restrict__ batch,
                                              int* __restrict__ gstart,
                                              const int* __restrict__ dst,
                                              unsigned int* __restrict__ histw) {
    __shared__ unsigned int lh[12500];         // only hist blocks use it
    const int b = blockIdx.x, t = threadIdx.x;
    if (b < PP) {                              // hist chunk b
        for (int w = t; w < 12500; w += 512) lh[w] = 0u;
        __syncthreads();
        const int e1 = (b + 1) * EPP;
        for (int e = b * EPP + t; e < e1; e += 512) {
            int d = dst[e];
            atomicAdd(&lh[d >> 2], 1u << (8 * (d & 3)));
        }
        __syncthreads();
        for (int w = t; w < 12500; w += 512) histw[(size_t)b * 12500 + w] = lh[w];
    } else if (b < PP + 64) {
        int o = (b - PP) * 512 + t;            // 0..32767
        const float* W = (o < 16384) ? W1 : W2;
        unsigned short* WT = (o < 16384) ? WT1 : WT2;
        int oo = o & 16383;
        int c = oo >> 7, k = oo & 127;
        WT[oo] = f2bf(W[k * 128 + c]);
    } else if (b == PP + 64) {
        if (t <= GG) {
            int lo = 0, hi = NN;
            while (lo < hi) {
                int mid = (lo + hi) >> 1;
                if (batch[mid] < t) lo = mid + 1; else hi = mid;
            }
            gstart[t] = lo;
        }
    } else {
        int o = (b - PP - 65) * 512 + t;       // 8 floats each, guard 800000
        if (o < 800000) {
            const float4* xp = (const float4*)x + (size_t)o * 2;
            float4 f0 = xp[0], f1 = xp[1];
            uint4 v;
            v.x = (unsigned)f2bf(f0.x) | ((unsigned)f2bf(f0.y) << 16);
            v.y = (unsigned)f2bf(f0.z) | ((unsigned)f2bf(f0.w) << 16);
            v.z = (unsigned)f2bf(f1.x) | ((unsigned)f2bf(f1.y) << 16);
            v.w = (unsigned)f2bf(f1.z) | ((unsigned)f2bf(f1.w) << 16);
            ((uint4*)XB)[o] = v;
        }
    }
}
#define PREPB (PP + 65 + 1563)   // 192 hist + 64 W + 1 gstart + 1563 conv

// ---- scanA: per-node total count + per-chunk u8 cursor bases + block sums ----
__global__ __launch_bounds__(256) void k_scanA(const unsigned char* __restrict__ hist8,
                                               unsigned char* __restrict__ cb8,
                                               int* __restrict__ cnt,
                                               int* __restrict__ bs) {
    int i = blockIdx.x * 256 + threadIdx.x;
    int run = 0;
    if (i < NN) {
        for (int p = 0; p < PP; p += 32) {
            unsigned char hh[32];
#pragma unroll
            for (int q = 0; q < 32; q++) hh[q] = hist8[(size_t)(p + q) * 50000 + i];
#pragma unroll
            for (int q = 0; q < 32; q++) {
                cb8[(size_t)(p + q) * 50000 + i] = (unsigned char)run;
                run += hh[q];
            }
        }
        cnt[i] = run;
    }
    int v = run;
#pragma unroll
    for (int o = 32; o >= 1; o >>= 1) v += __shfl_down(v, o, 64);
    __shared__ int ws[4];
    if ((threadIdx.x & 63) == 0) ws[threadIdx.x >> 6] = v;
    __syncthreads();
    if (threadIdx.x == 0) bs[blockIdx.x] = ws[0] + ws[1] + ws[2] + ws[3];
}

// ---- scanBC: redundant block-sum scan in LDS + per-chunk scan -> rowptr ----
__global__ __launch_bounds__(256) void k_scanBC(const int* __restrict__ bs,
                                                const int* __restrict__ cnt,
                                                int* __restrict__ rowptr) {
    __shared__ int sb[256];
    __shared__ int sc[256];
    const int t = threadIdx.x, b = blockIdx.x;
    int vb = (t < NBLK) ? bs[t] : 0;
    sb[t] = vb;
    __syncthreads();
    for (int off = 1; off < 256; off <<= 1) {
        int add = (t >= off) ? sb[t - off] : 0;
        __syncthreads();
        sb[t] += add;
        __syncthreads();
    }
    const int boff = (b > 0) ? sb[b - 1] : 0;
    const int i = b * 256 + t;
    int v = (i < NN) ? cnt[i] : 0;
    sc[t] = v;
    __syncthreads();
    for (int off = 1; off < 256; off <<= 1) {
        int add = (t >= off) ? sc[t - off] : 0;
        __syncthreads();
        sc[t] += add;
        __syncthreads();
    }
    int excl = sc[t] - v + boff;
    if (i < NN) rowptr[i] = excl;
    if (i == 0) rowptr[NN] = EE;
}

// ---- fill: replay chunk with LDS returning atomics -> bucket (src, ew) ----
__global__ __launch_bounds__(512) void k_fill(const int* __restrict__ src,
                                              const int* __restrict__ dst,
                                              const float* __restrict__ ew,
                                              const int* __restrict__ rowptr,
                                              const unsigned char* __restrict__ cb8,
                                              int2* __restrict__ bucket) {
    __shared__ unsigned int lh[12500];
    const int b = blockIdx.x, t = threadIdx.x;
    for (int w = t; w < 12500; w += 512) lh[w] = 0u;
    __syncthreads();
    const int e1 = (b + 1) * EPP;
    for (int e = b * EPP + t; e < e1; e += 512) {
        int d = dst[e];
        int sh = 8 * (d & 3);
        unsigned int old = atomicAdd(&lh[d >> 2], 1u << sh);
        int lr = (int)((old >> sh) & 0xffu);
        int pos = rowptr[d] + (int)cb8[(size_t)b * 50000 + d] + lr;
        bucket[pos] = make_int2(src[e], __float_as_int(ew[e]));
    }
}

// ---- degsum: segmented sum of ew over each node's CSR segment -> dinv ----
__global__ __launch_bounds__(256) void k_degsum(const int* __restrict__ rowptr,
                                                const long long* __restrict__ bucket,
                                                float* __restrict__ dinv) {
    int n = blockIdx.x * 256 + threadIdx.x;
    if (n < NN) {
        float s = 0.f;
        const int e1 = rowptr[n + 1];
        for (int e = rowptr[n]; e < e1; e++) {
            int ss; float w;
            ntbucket(&bucket[e], ss, w);
            s += w;
        }
        dinv[n] = rsqrtf(s + 1.0f);
    }
}

// ---- MFMA GEMM (bf16 in, bf16 out), async global_load_lds staging ----
// LDS linear; source column pre-swizzled slot^=(row&7) (both-sides rule #21).
__global__ __launch_bounds__(256, 3) void k_gemm(const unsigned short* __restrict__ Xin,
                                                 const unsigned short* __restrict__ Wt,
                                                 unsigned short* __restrict__ Y,
                                                 int nrows) {
    __shared__ char smem[49152];
    const int tid = threadIdx.x;
    const int lane = tid & 63, w = tid >> 6;
    const int r0 = blockIdx.x * 64;
    const char* Wb = (const char*)Wt;
    const char* Xb = (const char*)Xin;

#pragma unroll
    for (int j = 0; j < 12; j++) {
        const int base = (j * 4 + w) * 64;     // chunk index of lane 0 (uniform)
        const int ci = base + lane;            // 0..3071
        char* ldst = smem + (size_t)base * 16;
        if (base < 2048) {
            int row = ci >> 4, slot = ci & 15;
            ld16(Wb + row * 256 + ((slot ^ (row & 7)) * 16), ldst);
        } else {
            int xci = ci - 2048;
            int row = xci >> 4, slot = xci & 15;
            ld16(Xb + (size_t)(r0 + row) * 256 + ((slot ^ (row & 7)) * 16), ldst);
        }
    }
    __syncthreads();

    const int wr = (w >> 1) * 32, wc = (w & 1) * 64;
    const int lr = lane & 15, lg = lane >> 4;
    f32x4 acc[2][4];
#pragma unroll
    for (int a = 0; a < 2; a++)
#pragma unroll
        for (int c = 0; c < 4; c++) acc[a][c] = (f32x4){0.f, 0.f, 0.f, 0.f};

#pragma unroll
    for (int t = 0; t < 4; t++) {
        const int kb = t * 64 + lg * 16;
        bf16x8 af[2], bf[4];
#pragma unroll
        for (int i = 0; i < 2; i++) {
            int ar = wr + i * 16 + lr;
            af[i] = *(const bf16x8*)(smem + 32768 + ar * 256 + (kb ^ ((ar & 7) << 4)));
        }
#pragma unroll
        for (int i = 0; i < 4; i++) {
            int bc = wc + i * 16 + lr;
            bf[i] = *(const bf16x8*)(smem + bc * 256 + (kb ^ ((bc & 7) << 4)));
        }
#pragma unroll
        for (int fr = 0; fr < 2; fr++)
#pragma unroll
            for (int fc = 0; fc < 4; fc++)
                acc[fr][fc] = __builtin_amdgcn_mfma_f32_16x16x32_bf16(af[fr], bf[fc], acc[fr][fc], 0, 0, 0);
    }

    __syncthreads();
#pragma unroll
    for (int fr = 0; fr < 2; fr++)
#pragma unroll
        for (int fc = 0; fc < 4; fc++)
#pragma unroll
            for (int j = 0; j < 4; j++) {
                int row = wr + fr * 16 + lg * 4 + j;
                int col = wc + fc * 16 + lr;
                *(unsigned short*)(smem + row * 272 + col * 2) = f2bf(acc[fr][fc][j]);
            }
    __syncthreads();
#pragma unroll
    for (int j = 0; j < 4; j++) {
        int ci = tid + 256 * j;
        int row = ci >> 4, slot = ci & 15;
        int grow = r0 + row;
        if (grow < nrows)
            ((uint4*)(Y + (size_t)grow * 128))[slot] = *(const uint4*)(smem + row * 272 + slot * 16);
    }
}

// ---- gather-aggregate + self-loop + bias + relu (bf16 in/out) ----
// One wave per node; 4 edge-groups x 4-deep unroll = 16 row loads in flight.
// bucket streamed with nontemporal 8B loads (read once; keep XW rows in L2).
__global__ __launch_bounds__(256) void k_gather(const unsigned short* __restrict__ XW,
                                                const int* __restrict__ rowptr,
                                                const long long* __restrict__ bucket,
                                                const float* __restrict__ dinv,
                                                const float* __restrict__ b,
                                                unsigned short* __restrict__ H) {
    const int wv = threadIdx.x >> 6, lane = threadIdx.x & 63;
    const int n = blockIdx.x * 4 + wv;
    if (n >= NN) return;
    const int eg = lane >> 4;        // edge group 0..3
    const int fl = lane & 15;        // 16B feature slot
    const float di = dinv[n];
    const float sl = di * di;
    uint4 su = ((const uint4*)(XW + (size_t)n * 128))[fl];
    float acc[8];
#pragma unroll
    for (int q = 0; q < 8; q++) acc[q] = 0.f;
    const int e0 = rowptr[n], e1 = rowptr[n + 1];
    int e = e0 + eg;
    for (; e + 12 < e1; e += 16) {   // 4 edges per group per iter
        int s0, s1, s2, s3;
        float w0, w1, w2, w3;
        ntbucket(&bucket[e], s0, w0);
        ntbucket(&bucket[e + 4], s1, w1);
        ntbucket(&bucket[e + 8], s2, w2);
        ntbucket(&bucket[e + 12], s3, w3);
        float nm0 = dinv[s0] * w0 * di;
        float nm1 = dinv[s1] * w1 * di;
        float nm2 = dinv[s2] * w2 * di;
        float nm3 = dinv[s3] * w3 * di;
        uint4 v0 = ((const uint4*)(XW + (size_t)s0 * 128))[fl];
        uint4 v1 = ((const uint4*)(XW + (size_t)s1 * 128))[fl];
        uint4 v2 = ((const uint4*)(XW + (size_t)s2 * 128))[fl];
        uint4 v3 = ((const uint4*)(XW + (size_t)s3 * 128))[fl];
        unsigned int u0[4] = {v0.x, v0.y, v0.z, v0.w};
        unsigned int u1[4] = {v1.x, v1.y, v1.z, v1.w};
        unsigned int u2[4] = {v2.x, v2.y, v2.z, v2.w};
        unsigned int u3[4] = {v3.x, v3.y, v3.z, v3.w};
#pragma unroll
        for (int q = 0; q < 4; q++) {
            acc[2 * q]     = fmaf(__uint_as_float(u0[q] << 16), nm0, acc[2 * q]);
            acc[2 * q + 1] = fmaf(__uint_as_float(u0[q] & 0xffff0000u), nm0, acc[2 * q + 1]);
            acc[2 * q]     = fmaf(__uint_as_float(u1[q] << 16), nm1, acc[2 * q]);
            acc[2 * q + 1] = fmaf(__uint_as_float(u1[q] & 0xffff0000u), nm1, acc[2 * q + 1]);
            acc[2 * q]     = fmaf(__uint_as_float(u2[q] << 16), nm2, acc[2 * q]);
            acc[2 * q + 1] = fmaf(__uint_as_float(u2[q] & 0xffff0000u), nm2, acc[2 * q + 1]);
            acc[2 * q]     = fmaf(__uint_as_float(u3[q] << 16), nm3, acc[2 * q]);
            acc[2 * q + 1] = fmaf(__uint_as_float(u3[q] & 0xffff0000u), nm3, acc[2 * q + 1]);
        }
    }
    for (; e < e1; e += 4) {         // tail, stride 4 per group
        int ss; float ww;
        ntbucket(&bucket[e], ss, ww);
        float nm = dinv[ss] * ww * di;
        uint4 v = ((const uint4*)(XW + (size_t)ss * 128))[fl];
        unsigned int uu[4] = {v.x, v.y, v.z, v.w};
#pragma unroll
        for (int q = 0; q < 4; q++) {
            acc[2 * q]     = fmaf(__uint_as_float(uu[q] << 16), nm, acc[2 * q]);
            acc[2 * q + 1] = fmaf(__uint_as_float(uu[q] & 0xffff0000u), nm, acc[2 * q + 1]);
        }
    }
#pragma unroll
    for (int q = 0; q < 8; q++) {
        acc[q] += __shfl_xor(acc[q], 16);
        acc[q] += __shfl_xor(acc[q], 32);
    }
    if (eg == 0) {
        unsigned int us[4] = {su.x, su.y, su.z, su.w};
        float4 b0 = ((const float4*)b)[fl * 2];
        float4 b1 = ((const float4*)b)[fl * 2 + 1];
        float bb[8] = {b0.x, b0.y, b0.z, b0.w, b1.x, b1.y, b1.z, b1.w};
        float r[8];
#pragma unroll
        for (int q = 0; q < 4; q++) {
            r[2 * q]     = fmaxf(fmaf(__uint_as_float(us[q] << 16), sl, acc[2 * q]) + bb[2 * q], 0.f);
            r[2 * q + 1] = fmaxf(fmaf(__uint_as_float(us[q] & 0xffff0000u), sl, acc[2 * q + 1]) + bb[2 * q + 1], 0.f);
        }
        uint4 o;
        o.x = (unsigned)f2bf(r[0]) | ((unsigned)f2bf(r[1]) << 16);
        o.y = (unsigned)f2bf(r[2]) | ((unsigned)f2bf(r[3]) << 16);
        o.z = (unsigned)f2bf(r[4]) | ((unsigned)f2bf(r[5]) << 16);
        o.w = (unsigned)f2bf(r[6]) | ((unsigned)f2bf(r[7]) << 16);
        ((uint4*)(H + (size_t)n * 128))[fl] = o;
    }
}

// ---- fused pooling + head: one 512-thread block per graph, no atomics ----
__global__ __launch_bounds__(512) void k_poolhead(const unsigned short* __restrict__ H,
                                                  const int* __restrict__ gstart,
                                                  const float* __restrict__ linW,
                                                  const float* __restrict__ linb,
                                                  float* __restrict__ out) {
    __shared__ float lmx[1024], lsm[1024];
    __shared__ float mxf[128], mnf[128];
    const int g = blockIdx.x, t = threadIdx.x;
    const int slice = t >> 6;
    const int fp = t & 63;
    const int n0 = gstart[g], n1 = gstart[g + 1];
    float mx0 = 0.f, mx1 = 0.f, sm0 = 0.f, sm1 = 0.f;   // h >= 0 post-relu
    for (int n = n0 + slice; n < n1; n += 8) {
        unsigned int u = *(const unsigned int*)(H + (size_t)n * 128 + fp * 2);
        float v0 = bf2f((unsigned short)(u & 0xffffu));
        float v1 = bf2f((unsigned short)(u >> 16));
        mx0 = fmaxf(mx0, v0); mx1 = fmaxf(mx1, v1);
        sm0 += v0; sm1 += v1;
    }
    lmx[slice * 128 + fp * 2] = mx0; lmx[slice * 128 + fp * 2 + 1] = mx1;
    lsm[slice * 128 + fp * 2] = sm0; lsm[slice * 128 + fp * 2 + 1] = sm1;
    __syncthreads();
    if (t < 128) {
        float m = 0.f, s = 0.f;
#pragma unroll
        for (int q = 0; q < 8; q++) {
            m = fmaxf(m, lmx[q * 128 + t]);
            s += lsm[q * 128 + t];
        }
        mxf[t] = m;
        mnf[t] = s / fmaxf((float)(n1 - n0), 1.0f);
    }
    __syncthreads();
    if (t < CC) {
        float z = linb[t];
        for (int f = 0; f < 128; f++) {
            z = fmaf(mxf[f], linW[f * CC + t], z);
            z = fmaf(mnf[f], linW[(128 + f) * CC + t], z);
        }
        float m = z;
        for (int o = 8; o >= 1; o >>= 1) m = fmaxf(m, __shfl_xor(m, o, 16));
        float ex = expf(z - m), s = ex;
        for (int o = 8; o >= 1; o >>= 1) s += __shfl_xor(s, o, 16);
        out[g * CC + t] = z - m - logf(s);
    }
}

extern "C" void kernel_launch(void* const* d_in, const int* in_sizes, int n_in,
                              void* d_out, int out_size, void* d_ws, size_t ws_size,
                              hipStream_t stream) {
    const float* x    = (const float*)d_in[0];
    const int*   ei   = (const int*)d_in[1];
    const float* ew   = (const float*)d_in[2];
    const int*   batch= (const int*)d_in[3];
    const float* W1   = (const float*)d_in[4];
    const float* b1   = (const float*)d_in[5];
    const float* W2   = (const float*)d_in[6];
    const float* b2   = (const float*)d_in[7];
    const float* linW = (const float*)d_in[8];
    const float* linb = (const float*)d_in[9];
    float* out = (float*)d_out;

    // workspace layout: 16B-aligned buffers first
    unsigned short* YB = (unsigned short*)d_ws;              // [N,128] bf16 gemm out
    unsigned short* HB = YB + (size_t)NN * 128;              // [N,128] bf16 gather out
    unsigned short* XB = HB + (size_t)NN * 128;              // [N,128] bf16 input / h2
    unsigned short* WT1 = XB + (size_t)NN * 128;             // [128*128]
    unsigned short* WT2 = WT1 + 128 * 128;                   // [128*128]
    int2*  BUCKET = (int2*)(WT2 + 128 * 128);                // [E] (src, ew)
    float* DINV   = (float*)(BUCKET + EE);                   // [N]
    int*   ROWPTR = (int*)(DINV + NN);                       // [N+1]
    int*   CNT    = ROWPTR + NN + 1;                         // [N]
    int*   GSTART = CNT + NN;                                // [G+1]
    int*   BS     = GSTART + GG + 1;                         // [NBLK]
    unsigned int* HISTW = (unsigned int*)(BS + NBLK + 1);    // [PP][12500] u8x4
    unsigned char* CB8 = (unsigned char*)(HISTW + (size_t)PP * 12500); // [PP][50000] u8

    const int* src = ei;
    const int* dst = ei + EE;

    // prep: hist | W transpose | gstart | x->bf16
    k_prep<<<PREPB, 512, 0, stream>>>(x, XB, W1, W2, WT1, WT2, batch, GSTART, dst, HISTW);

    // layer-1 GEMM (independent of CSR build)
    k_gemm<<<GEMMB, 256, 0, stream>>>(XB, WT1, YB, NN);

    // CSR build — no global atomics anywhere
    k_scanA<<<NBLK, 256, 0, stream>>>((const unsigned char*)HISTW, CB8, CNT, BS);
    k_scanBC<<<NBLK, 256, 0, stream>>>(BS, CNT, ROWPTR);
    k_fill<<<PP, 512, 0, stream>>>(src, dst, ew, ROWPTR, CB8, BUCKET);
    k_degsum<<<NBLK, 256, 0, stream>>>(ROWPTR, (const long long*)BUCKET, DINV);

    // layer 1 aggregate
    k_gather<<<(NN + 3) / 4, 256, 0, stream>>>(YB, ROWPTR, (const long long*)BUCKET, DINV, b1, HB);

    // layer 2
    k_gemm<<<GEMMB, 256, 0, stream>>>(HB, WT2, YB, NN);
    k_gather<<<(NN + 3) / 4, 256, 0, stream>>>(YB, ROWPTR, (const long long*)BUCKET, DINV, b2, XB);

    // pooling + head (one block per graph)
    k_poolhead<<<GG, 512, 0, stream>>>(XB, GSTART, linW, linb, out);
}

// Round 18
// 162.849 us; speedup vs baseline: 1.4301x; 1.0005x over previous
//
#include <hip/hip_runtime.h>
#include <hip/hip_bf16.h>

#define NN 50000
#define EE 600000
#define FH 128
#define GG 128
#define CC 16
#define NBLK ((NN + 255) / 256)   // 196 node blocks
#define GEMMB 782                 // 64-row gemm tiles
#define PP 192                    // edge chunks (hist/fill blocks)
#define EPP 3125                  // edges per chunk (192*3125 == 600000)

typedef __attribute__((ext_vector_type(8))) short bf16x8;
typedef __attribute__((ext_vector_type(4))) float f32x4;

static __device__ __forceinline__ unsigned short f2bf(float f) {
    union { float f; unsigned int u; } v; v.f = f;
    unsigned int r = v.u + 0x7fffu + ((v.u >> 16) & 1u);   // RNE
    return (unsigned short)(r >> 16);
}
static __device__ __forceinline__ float bf2f(unsigned short h) {
    union { unsigned int u; float f; } v; v.u = ((unsigned int)h) << 16;
    return v.f;
}
// async global->LDS, 16B per lane; lds base must be wave-uniform
static __device__ __forceinline__ void ld16(const void* g, void* l) {
    __builtin_amdgcn_global_load_lds((const __attribute__((address_space(1))) void*)g,
                                     (__attribute__((address_space(3))) void*)l, 16, 0, 0);
}
// nontemporal 8B bucket load: lo 32b = src index, hi 32b = ew bits
static __device__ __forceinline__ void ntbucket(const long long* p, int& s, float& w) {
    long long v = __builtin_nontemporal_load(p);
    s = (int)(v & 0xffffffffLL);
    w = __uint_as_float((unsigned int)((unsigned long long)v >> 32));
}

// ---- prep (512 thr): W transpose | gstart | x->bf16 | per-chunk dst hist ----
__global__ __launch_bounds__(512) void k_prep(const float* __restrict__ x,
                                              unsigned short* __restrict__ XB,
                                              const float* __restrict__ W1,
                                              const float* __restrict__ W2,
                                              unsigned short* __restrict__ WT1,
                                              unsigned short* __restrict__ WT2,
                                              const int* __restrict__ batch,
                                              int* __restrict__ gstart,
                                              const int* __restrict__ dst,
                                              unsigned int* __restrict__ histw) {
    __shared__ unsigned int lh[12500];         // only hist blocks use it
    const int b = blockIdx.x, t = threadIdx.x;
    if (b < PP) {                              // hist chunk b
        for (int w = t; w < 12500; w += 512) lh[w] = 0u;
        __syncthreads();
        const int e1 = (b + 1) * EPP;
        for (int e = b * EPP + t; e < e1; e += 512) {
            int d = dst[e];
            atomicAdd(&lh[d >> 2], 1u << (8 * (d & 3)));
        }
        __syncthreads();
        for (int w = t; w < 12500; w += 512) histw[(size_t)b * 12500 + w] = lh[w];
    } else if (b < PP + 64) {
        int o = (b - PP) * 512 + t;            // 0..32767
        const float* W = (o < 16384) ? W1 : W2;
        unsigned short* WT = (o < 16384) ? WT1 : WT2;
        int oo = o & 16383;
        int c = oo >> 7, k = oo & 127;
        WT[oo] = f2bf(W[k * 128 + c]);
    } else if (b == PP + 64) {
        if (t <= GG) {
            int lo = 0, hi = NN;
            while (lo < hi) {
                int mid = (lo + hi) >> 1;
                if (batch[mid] < t) lo = mid + 1; else hi = mid;
            }
            gstart[t] = lo;
        }
    } else {
        int o = (b - PP - 65) * 512 + t;       // 8 floats each, guard 800000
        if (o < 800000) {
            const float4* xp = (const float4*)x + (size_t)o * 2;
            float4 f0 = xp[0], f1 = xp[1];
            uint4 v;
            v.x = (unsigned)f2bf(f0.x) | ((unsigned)f2bf(f0.y) << 16);
            v.y = (unsigned)f2bf(f0.z) | ((unsigned)f2bf(f0.w) << 16);
            v.z = (unsigned)f2bf(f1.x) | ((unsigned)f2bf(f1.y) << 16);
            v.w = (unsigned)f2bf(f1.z) | ((unsigned)f2bf(f1.w) << 16);
            ((uint4*)XB)[o] = v;
        }
    }
}
#define PREPB (PP + 65 + 1563)   // 192 hist + 64 W + 1 gstart + 1563 conv

// ---- scanA: per-node total count + per-chunk u8 cursor bases + block sums ----
__global__ __launch_bounds__(256) void k_scanA(const unsigned char* __restrict__ hist8,
                                               unsigned char* __restrict__ cb8,
                                               int* __restrict__ cnt,
                                               int* __restrict__ bs) {
    int i = blockIdx.x * 256 + threadIdx.x;
    int run = 0;
    if (i < NN) {
        for (int p = 0; p < PP; p += 32) {
            unsigned char hh[32];
#pragma unroll
            for (int q = 0; q < 32; q++) hh[q] = hist8[(size_t)(p + q) * 50000 + i];
#pragma unroll
            for (int q = 0; q < 32; q++) {
                cb8[(size_t)(p + q) * 50000 + i] = (unsigned char)run;
                run += hh[q];
            }
        }
        cnt[i] = run;
    }
    int v = run;
#pragma unroll
    for (int o = 32; o >= 1; o >>= 1) v += __shfl_down(v, o, 64);
    __shared__ int ws[4];
    if ((threadIdx.x & 63) == 0) ws[threadIdx.x >> 6] = v;
    __syncthreads();
    if (threadIdx.x == 0) bs[blockIdx.x] = ws[0] + ws[1] + ws[2] + ws[3];
}

// ---- scanBC: redundant block-sum scan in LDS + per-chunk scan -> rowptr ----
__global__ __launch_bounds__(256) void k_scanBC(const int* __restrict__ bs,
                                                const int* __restrict__ cnt,
                                                int* __restrict__ rowptr) {
    __shared__ int sb[256];
    __shared__ int sc[256];
    const int t = threadIdx.x, b = blockIdx.x;
    int vb = (t < NBLK) ? bs[t] : 0;
    sb[t] = vb;
    __syncthreads();
    for (int off = 1; off < 256; off <<= 1) {
        int add = (t >= off) ? sb[t - off] : 0;
        __syncthreads();
        sb[t] += add;
        __syncthreads();
    }
    const int boff = (b > 0) ? sb[b - 1] : 0;
    const int i = b * 256 + t;
    int v = (i < NN) ? cnt[i] : 0;
    sc[t] = v;
    __syncthreads();
    for (int off = 1; off < 256; off <<= 1) {
        int add = (t >= off) ? sc[t - off] : 0;
        __syncthreads();
        sc[t] += add;
        __syncthreads();
    }
    int excl = sc[t] - v + boff;
    if (i < NN) rowptr[i] = excl;
    if (i == 0) rowptr[NN] = EE;
}

// ---- fill: replay chunk with LDS returning atomics -> bucket (src, ew) ----
__global__ __launch_bounds__(512) void k_fill(const int* __restrict__ src,
                                              const int* __restrict__ dst,
                                              const float* __restrict__ ew,
                                              const int* __restrict__ rowptr,
                                              const unsigned char* __restrict__ cb8,
                                              int2* __restrict__ bucket) {
    __shared__ unsigned int lh[12500];
    const int b = blockIdx.x, t = threadIdx.x;
    for (int w = t; w < 12500; w += 512) lh[w] = 0u;
    __syncthreads();
    const int e1 = (b + 1) * EPP;
    for (int e = b * EPP + t; e < e1; e += 512) {
        int d = dst[e];
        int sh = 8 * (d & 3);
        unsigned int old = atomicAdd(&lh[d >> 2], 1u << sh);
        int lr = (int)((old >> sh) & 0xffu);
        int pos = rowptr[d] + (int)cb8[(size_t)b * 50000 + d] + lr;
        bucket[pos] = make_int2(src[e], __float_as_int(ew[e]));
    }
}

// ---- degsum: segmented sum of ew over each node's CSR segment -> dinv ----
__global__ __launch_bounds__(256) void k_degsum(const int* __restrict__ rowptr,
                                                const long long* __restrict__ bucket,
                                                float* __restrict__ dinv) {
    int n = blockIdx.x * 256 + threadIdx.x;
    if (n < NN) {
        float s = 0.f;
        const int e1 = rowptr[n + 1];
        for (int e = rowptr[n]; e < e1; e++) {
            int ss; float w;
            ntbucket(&bucket[e], ss, w);
            s += w;
        }
        dinv[n] = rsqrtf(s + 1.0f);
    }
}

// ---- MFMA GEMM (bf16 in, bf16 out), async global_load_lds staging ----
// LDS linear; source column pre-swizzled slot^=(row&7) (both-sides rule #21).
__global__ __launch_bounds__(256, 3) void k_gemm(const unsigned short* __restrict__ Xin,
                                                 const unsigned short* __restrict__ Wt,
                                                 unsigned short* __restrict__ Y,
                                                 int nrows) {
    __shared__ char smem[49152];
    const int tid = threadIdx.x;
    const int lane = tid & 63, w = tid >> 6;
    const int r0 = blockIdx.x * 64;
    const char* Wb = (const char*)Wt;
    const char* Xb = (const char*)Xin;

#pragma unroll
    for (int j = 0; j < 12; j++) {
        const int base = (j * 4 + w) * 64;     // chunk index of lane 0 (uniform)
        const int ci = base + lane;            // 0..3071
        char* ldst = smem + (size_t)base * 16;
        if (base < 2048) {
            int row = ci >> 4, slot = ci & 15;
            ld16(Wb + row * 256 + ((slot ^ (row & 7)) * 16), ldst);
        } else {
            int xci = ci - 2048;
            int row = xci >> 4, slot = xci & 15;
            ld16(Xb + (size_t)(r0 + row) * 256 + ((slot ^ (row & 7)) * 16), ldst);
        }
    }
    __syncthreads();

    const int wr = (w >> 1) * 32, wc = (w & 1) * 64;
    const int lr = lane & 15, lg = lane >> 4;
    f32x4 acc[2][4];
#pragma unroll
    for (int a = 0; a < 2; a++)
#pragma unroll
        for (int c = 0; c < 4; c++) acc[a][c] = (f32x4){0.f, 0.f, 0.f, 0.f};

#pragma unroll
    for (int t = 0; t < 4; t++) {
        const int kb = t * 64 + lg * 16;
        bf16x8 af[2], bf[4];
#pragma unroll
        for (int i = 0; i < 2; i++) {
            int ar = wr + i * 16 + lr;
            af[i] = *(const bf16x8*)(smem + 32768 + ar * 256 + (kb ^ ((ar & 7) << 4)));
        }
#pragma unroll
        for (int i = 0; i < 4; i++) {
            int bc = wc + i * 16 + lr;
            bf[i] = *(const bf16x8*)(smem + bc * 256 + (kb ^ ((bc & 7) << 4)));
        }
#pragma unroll
        for (int fr = 0; fr < 2; fr++)
#pragma unroll
            for (int fc = 0; fc < 4; fc++)
                acc[fr][fc] = __builtin_amdgcn_mfma_f32_16x16x32_bf16(af[fr], bf[fc], acc[fr][fc], 0, 0, 0);
    }

    __syncthreads();
#pragma unroll
    for (int fr = 0; fr < 2; fr++)
#pragma unroll
        for (int fc = 0; fc < 4; fc++)
#pragma unroll
            for (int j = 0; j < 4; j++) {
                int row = wr + fr * 16 + lg * 4 + j;
                int col = wc + fc * 16 + lr;
                *(unsigned short*)(smem + row * 272 + col * 2) = f2bf(acc[fr][fc][j]);
            }
    __syncthreads();
#pragma unroll
    for (int j = 0; j < 4; j++) {
        int ci = tid + 256 * j;
        int row = ci >> 4, slot = ci & 15;
        int grow = r0 + row;
        if (grow < nrows)
            ((uint4*)(Y + (size_t)grow * 128))[slot] = *(const uint4*)(smem + row * 272 + slot * 16);
    }
}

// ---- gather-aggregate + self-loop + bias + relu (bf16 in/out) ----
// One wave per node; 4 edge-groups x 4-deep unroll = 16 row loads in flight.
// bucket streamed with nontemporal 8B loads (read once; keep XW rows in L2).
__global__ __launch_bounds__(256) void k_gather(const unsigned short* __restrict__ XW,
                                                const int* __restrict__ rowptr,
                                                const long long* __restrict__ bucket,
                                                const float* __restrict__ dinv,
                                                const float* __restrict__ b,
                                                unsigned short* __restrict__ H) {
    const int wv = threadIdx.x >> 6, lane = threadIdx.x & 63;
    const int n = blockIdx.x * 4 + wv;
    if (n >= NN) return;
    const int eg = lane >> 4;        // edge group 0..3
    const int fl = lane & 15;        // 16B feature slot
    const float di = dinv[n];
    const float sl = di * di;
    uint4 su = ((const uint4*)(XW + (size_t)n * 128))[fl];
    float acc[8];
#pragma unroll
    for (int q = 0; q < 8; q++) acc[q] = 0.f;
    const int e0 = rowptr[n], e1 = rowptr[n + 1];
    int e = e0 + eg;
    for (; e + 12 < e1; e += 16) {   // 4 edges per group per iter
        int s0, s1, s2, s3;
        float w0, w1, w2, w3;
        ntbucket(&bucket[e], s0, w0);
        ntbucket(&bucket[e + 4], s1, w1);
        ntbucket(&bucket[e + 8], s2, w2);
        ntbucket(&bucket[e + 12], s3, w3);
        float nm0 = dinv[s0] * w0 * di;
        float nm1 = dinv[s1] * w1 * di;
        float nm2 = dinv[s2] * w2 * di;
        float nm3 = dinv[s3] * w3 * di;
        uint4 v0 = ((const uint4*)(XW + (size_t)s0 * 128))[fl];
        uint4 v1 = ((const uint4*)(XW + (size_t)s1 * 128))[fl];
        uint4 v2 = ((const uint4*)(XW + (size_t)s2 * 128))[fl];
        uint4 v3 = ((const uint4*)(XW + (size_t)s3 * 128))[fl];
        unsigned int u0[4] = {v0.x, v0.y, v0.z, v0.w};
        unsigned int u1[4] = {v1.x, v1.y, v1.z, v1.w};
        unsigned int u2[4] = {v2.x, v2.y, v2.z, v2.w};
        unsigned int u3[4] = {v3.x, v3.y, v3.z, v3.w};
#pragma unroll
        for (int q = 0; q < 4; q++) {
            acc[2 * q]     = fmaf(__uint_as_float(u0[q] << 16), nm0, acc[2 * q]);
            acc[2 * q + 1] = fmaf(__uint_as_float(u0[q] & 0xffff0000u), nm0, acc[2 * q + 1]);
            acc[2 * q]     = fmaf(__uint_as_float(u1[q] << 16), nm1, acc[2 * q]);
            acc[2 * q + 1] = fmaf(__uint_as_float(u1[q] & 0xffff0000u), nm1, acc[2 * q + 1]);
            acc[2 * q]     = fmaf(__uint_as_float(u2[q] << 16), nm2, acc[2 * q]);
            acc[2 * q + 1] = fmaf(__uint_as_float(u2[q] & 0xffff0000u), nm2, acc[2 * q + 1]);
            acc[2 * q]     = fmaf(__uint_as_float(u3[q] << 16), nm3, acc[2 * q]);
            acc[2 * q + 1] = fmaf(__uint_as_float(u3[q] & 0xffff0000u), nm3, acc[2 * q + 1]);
        }
    }
    for (; e < e1; e += 4) {         // tail, stride 4 per group
        int ss; float ww;
        ntbucket(&bucket[e], ss, ww);
        float nm = dinv[ss] * ww * di;
        uint4 v = ((const uint4*)(XW + (size_t)ss * 128))[fl];
        unsigned int uu[4] = {v.x, v.y, v.z, v.w};
#pragma unroll
        for (int q = 0; q < 4; q++) {
            acc[2 * q]     = fmaf(__uint_as_float(uu[q] << 16), nm, acc[2 * q]);
            acc[2 * q + 1] = fmaf(__uint_as_float(uu[q] & 0xffff0000u), nm, acc[2 * q + 1]);
        }
    }
#pragma unroll
    for (int q = 0; q < 8; q++) {
        acc[q] += __shfl_xor(acc[q], 16);
        acc[q] += __shfl_xor(acc[q], 32);
    }
    if (eg == 0) {
        unsigned int us[4] = {su.x, su.y, su.z, su.w};
        float4 b0 = ((const float4*)b)[fl * 2];
        float4 b1 = ((const float4*)b)[fl * 2 + 1];
        float bb[8] = {b0.x, b0.y, b0.z, b0.w, b1.x, b1.y, b1.z, b1.w};
        float r[8];
#pragma unroll
        for (int q = 0; q < 4; q++) {
            r[2 * q]     = fmaxf(fmaf(__uint_as_float(us[q] << 16), sl, acc[2 * q]) + bb[2 * q], 0.f);
            r[2 * q + 1] = fmaxf(fmaf(__uint_as_float(us[q] & 0xffff0000u), sl, acc[2 * q + 1]) + bb[2 * q + 1], 0.f);
        }
        uint4 o;
        o.x = (unsigned)f2bf(r[0]) | ((unsigned)f2bf(r[1]) << 16);
        o.y = (unsigned)f2bf(r[2]) | ((unsigned)f2bf(r[3]) << 16);
        o.z = (unsigned)f2bf(r[4]) | ((unsigned)f2bf(r[5]) << 16);
        o.w = (unsigned)f2bf(r[6]) | ((unsigned)f2bf(r[7]) << 16);
        ((uint4*)(H + (size_t)n * 128))[fl] = o;
    }
}

// ---- fused pooling + head: one 512-thread block per graph, no atomics ----
__global__ __launch_bounds__(512) void k_poolhead(const unsigned short* __restrict__ H,
                                                  const int* __restrict__ gstart,
                                                  const float* __restrict__ linW,
                                                  const float* __restrict__ linb,
                                                  float* __restrict__ out) {
    __shared__ float lmx[1024], lsm[1024];
    __shared__ float mxf[128], mnf[128];
    const int g = blockIdx.x, t = threadIdx.x;
    const int slice = t >> 6;
    const int fp = t & 63;
    const int n0 = gstart[g], n1 = gstart[g + 1];
    float mx0 = 0.f, mx1 = 0.f, sm0 = 0.f, sm1 = 0.f;   // h >= 0 post-relu
    for (int n = n0 + slice; n < n1; n += 8) {
        unsigned int u = *(const unsigned int*)(H + (size_t)n * 128 + fp * 2);
        float v0 = bf2f((unsigned short)(u & 0xffffu));
        float v1 = bf2f((unsigned short)(u >> 16));
        mx0 = fmaxf(mx0, v0); mx1 = fmaxf(mx1, v1);
        sm0 += v0; sm1 += v1;
    }
    lmx[slice * 128 + fp * 2] = mx0; lmx[slice * 128 + fp * 2 + 1] = mx1;
    lsm[slice * 128 + fp * 2] = sm0; lsm[slice * 128 + fp * 2 + 1] = sm1;
    __syncthreads();
    if (t < 128) {
        float m = 0.f, s = 0.f;
#pragma unroll
        for (int q = 0; q < 8; q++) {
            m = fmaxf(m, lmx[q * 128 + t]);
            s += lsm[q * 128 + t];
        }
        mxf[t] = m;
        mnf[t] = s / fmaxf((float)(n1 - n0), 1.0f);
    }
    __syncthreads();
    if (t < CC) {
        float z = linb[t];
        for (int f = 0; f < 128; f++) {
            z = fmaf(mxf[f], linW[f * CC + t], z);
            z = fmaf(mnf[f], linW[(128 + f) * CC + t], z);
        }
        float m = z;
        for (int o = 8; o >= 1; o >>= 1) m = fmaxf(m, __shfl_xor(m, o, 16));
        float ex = expf(z - m), s = ex;
        for (int o = 8; o >= 1; o >>= 1) s += __shfl_xor(s, o, 16);
        out[g * CC + t] = z - m - logf(s);
    }
}

extern "C" void kernel_launch(void* const* d_in, const int* in_sizes, int n_in,
                              void* d_out, int out_size, void* d_ws, size_t ws_size,
                              hipStream_t stream) {
    const float* x    = (const float*)d_in[0];
    const int*   ei   = (const int*)d_in[1];
    const float* ew   = (const float*)d_in[2];
    const int*   batch= (const int*)d_in[3];
    const float* W1   = (const float*)d_in[4];
    const float* b1   = (const float*)d_in[5];
    const float* W2   = (const float*)d_in[6];
    const float* b2   = (const float*)d_in[7];
    const float* linW = (const float*)d_in[8];
    const float* linb = (const float*)d_in[9];
    float* out = (float*)d_out;

    // workspace layout: 16B-aligned buffers first
    unsigned short* YB = (unsigned short*)d_ws;              // [N,128] bf16 gemm out
    unsigned short* HB = YB + (size_t)NN * 128;              // [N,128] bf16 gather out
    unsigned short* XB = HB + (size_t)NN * 128;              // [N,128] bf16 input / h2
    unsigned short* WT1 = XB + (size_t)NN * 128;             // [128*128]
    unsigned short* WT2 = WT1 + 128 * 128;                   // [128*128]
    int2*  BUCKET = (int2*)(WT2 + 128 * 128);                // [E] (src, ew)
    float* DINV   = (float*)(BUCKET + EE);                   // [N]
    int*   ROWPTR = (int*)(DINV + NN);                       // [N+1]
    int*   CNT    = ROWPTR + NN + 1;                         // [N]
    int*   GSTART = CNT + NN;                                // [G+1]
    int*   BS     = GSTART + GG + 1;                         // [NBLK]
    unsigned int* HISTW = (unsigned int*)(BS + NBLK + 1);    // [PP][12500] u8x4
    unsigned char* CB8 = (unsigned char*)(HISTW + (size_t)PP * 12500); // [PP][50000] u8

    const int* src = ei;
    const int* dst = ei + EE;

    // prep: hist | W transpose | gstart | x->bf16
    k_prep<<<PREPB, 512, 0, stream>>>(x, XB, W1, W2, WT1, WT2, batch, GSTART, dst, HISTW);

    // layer-1 GEMM (independent of CSR build)
    k_gemm<<<GEMMB, 256, 0, stream>>>(XB, WT1, YB, NN);

    // CSR build — no global atomics anywhere
    k_scanA<<<NBLK, 256, 0, stream>>>((const unsigned char*)HISTW, CB8, CNT, BS);
    k_scanBC<<<NBLK, 256, 0, stream>>>(BS, CNT, ROWPTR);
    k_fill<<<PP, 512, 0, stream>>>(src, dst, ew, ROWPTR, CB8, BUCKET);
    k_degsum<<<NBLK, 256, 0, stream>>>(ROWPTR, (const long long*)BUCKET, DINV);

    // layer 1 aggregate
    k_gather<<<(NN + 3) / 4, 256, 0, stream>>>(YB, ROWPTR, (const long long*)BUCKET, DINV, b1, HB);

    // layer 2
    k_gemm<<<GEMMB, 256, 0, stream>>>(HB, WT2, YB, NN);
    k_gather<<<(NN + 3) / 4, 256, 0, stream>>>(YB, ROWPTR, (const long long*)BUCKET, DINV, b2, XB);

    // pooling + head (one block per graph)
    k_poolhead<<<GG, 512, 0, stream>>>(XB, GSTART, linW, linb, out);
}

// Round 19
// 146.099 us; speedup vs baseline: 1.5940x; 1.1146x over previous
//
#include <hip/hip_runtime.h>
#include <hip/hip_bf16.h>

#define NN 50000
#define EE 600000
#define FH 128
#define GG 128
#define CC 16
#define NBLK ((NN + 255) / 256)   // 196 node blocks
#define GEMMB 782                 // 64-row gemm tiles
#define PP 192                    // edge chunks (hist/fill blocks)
#define EPP 3125                  // edges per chunk (192*3125 == 600000)

typedef __attribute__((ext_vector_type(8))) short bf16x8;
typedef __attribute__((ext_vector_type(4))) float f32x4;

static __device__ __forceinline__ unsigned short f2bf(float f) {
    union { float f; unsigned int u; } v; v.f = f;
    unsigned int r = v.u + 0x7fffu + ((v.u >> 16) & 1u);   // RNE
    return (unsigned short)(r >> 16);
}
static __device__ __forceinline__ float bf2f(unsigned short h) {
    union { unsigned int u; float f; } v; v.u = ((unsigned int)h) << 16;
    return v.f;
}
// async global->LDS, 16B per lane; lds base must be wave-uniform
static __device__ __forceinline__ void ld16(const void* g, void* l) {
    __builtin_amdgcn_global_load_lds((const __attribute__((address_space(1))) void*)g,
                                     (__attribute__((address_space(3))) void*)l, 16, 0, 0);
}

// ---- prep (512 thr): W transpose | gstart | x->bf16 | per-chunk dst hist ----
__global__ __launch_bounds__(512) void k_prep(const float* __restrict__ x,
                                              unsigned short* __restrict__ XB,
                                              const float* __restrict__ W1,
                                              const float* __restrict__ W2,
                                              unsigned short* __restrict__ WT1,
                                              unsigned short* __restrict__ WT2,
                                              const int* __restrict__ batch,
                                              int* __restrict__ gstart,
                                              const int* __restrict__ dst,
                                              unsigned int* __restrict__ histw) {
    __shared__ unsigned int lh[12500];         // only hist blocks use it
    const int b = blockIdx.x, t = threadIdx.x;
    if (b < PP) {                              // hist chunk b
        for (int w = t; w < 12500; w += 512) lh[w] = 0u;
        __syncthreads();
        const int e1 = (b + 1) * EPP;
        for (int e = b * EPP + t; e < e1; e += 512) {
            int d = dst[e];
            atomicAdd(&lh[d >> 2], 1u << (8 * (d & 3)));
        }
        __syncthreads();
        for (int w = t; w < 12500; w += 512) histw[(size_t)b * 12500 + w] = lh[w];
    } else if (b < PP + 64) {
        int o = (b - PP) * 512 + t;            // 0..32767
        const float* W = (o < 16384) ? W1 : W2;
        unsigned short* WT = (o < 16384) ? WT1 : WT2;
        int oo = o & 16383;
        int c = oo >> 7, k = oo & 127;
        WT[oo] = f2bf(W[k * 128 + c]);
    } else if (b == PP + 64) {
        if (t <= GG) {
            int lo = 0, hi = NN;
            while (lo < hi) {
                int mid = (lo + hi) >> 1;
                if (batch[mid] < t) lo = mid + 1; else hi = mid;
            }
            gstart[t] = lo;
        }
    } else {
        int o = (b - PP - 65) * 512 + t;       // 8 floats each, guard 800000
        if (o < 800000) {
            const float4* xp = (const float4*)x + (size_t)o * 2;
            float4 f0 = xp[0], f1 = xp[1];
            uint4 v;
            v.x = (unsigned)f2bf(f0.x) | ((unsigned)f2bf(f0.y) << 16);
            v.y = (unsigned)f2bf(f0.z) | ((unsigned)f2bf(f0.w) << 16);
            v.z = (unsigned)f2bf(f1.x) | ((unsigned)f2bf(f1.y) << 16);
            v.w = (unsigned)f2bf(f1.z) | ((unsigned)f2bf(f1.w) << 16);
            ((uint4*)XB)[o] = v;
        }
    }
}
#define PREPB (PP + 65 + 1563)   // 192 hist + 64 W + 1 gstart + 1563 conv

// ---- scanA: per-node total count + per-chunk u8 cursor bases + block sums ----
__global__ __launch_bounds__(256) void k_scanA(const unsigned char* __restrict__ hist8,
                                               unsigned char* __restrict__ cb8,
                                               int* __restrict__ cnt,
                                               int* __restrict__ bs) {
    int i = blockIdx.x * 256 + threadIdx.x;
    int run = 0;
    if (i < NN) {
        for (int p = 0; p < PP; p += 32) {
            unsigned char hh[32];
#pragma unroll
            for (int q = 0; q < 32; q++) hh[q] = hist8[(size_t)(p + q) * 50000 + i];
#pragma unroll
            for (int q = 0; q < 32; q++) {
                cb8[(size_t)(p + q) * 50000 + i] = (unsigned char)run;
                run += hh[q];
            }
        }
        cnt[i] = run;
    }
    int v = run;
#pragma unroll
    for (int o = 32; o >= 1; o >>= 1) v += __shfl_down(v, o, 64);
    __shared__ int ws[4];
    if ((threadIdx.x & 63) == 0) ws[threadIdx.x >> 6] = v;
    __syncthreads();
    if (threadIdx.x == 0) bs[blockIdx.x] = ws[0] + ws[1] + ws[2] + ws[3];
}

// ---- scanBC: redundant block-sum scan in LDS + per-chunk scan -> rowptr ----
__global__ __launch_bounds__(256) void k_scanBC(const int* __restrict__ bs,
                                                const int* __restrict__ cnt,
                                                int* __restrict__ rowptr) {
    __shared__ int sb[256];
    __shared__ int sc[256];
    const int t = threadIdx.x, b = blockIdx.x;
    int vb = (t < NBLK) ? bs[t] : 0;
    sb[t] = vb;
    __syncthreads();
    for (int off = 1; off < 256; off <<= 1) {
        int add = (t >= off) ? sb[t - off] : 0;
        __syncthreads();
        sb[t] += add;
        __syncthreads();
    }
    const int boff = (b > 0) ? sb[b - 1] : 0;
    const int i = b * 256 + t;
    int v = (i < NN) ? cnt[i] : 0;
    sc[t] = v;
    __syncthreads();
    for (int off = 1; off < 256; off <<= 1) {
        int add = (t >= off) ? sc[t - off] : 0;
        __syncthreads();
        sc[t] += add;
        __syncthreads();
    }
    int excl = sc[t] - v + boff;
    if (i < NN) rowptr[i] = excl;
    if (i == 0) rowptr[NN] = EE;
}

// ---- fill: replay chunk with LDS returning atomics -> bucket (src, ew) ----
__global__ __launch_bounds__(512) void k_fill(const int* __restrict__ src,
                                              const int* __restrict__ dst,
                                              const float* __restrict__ ew,
                                              const int* __restrict__ rowptr,
                                              const unsigned char* __restrict__ cb8,
                                              int2* __restrict__ bucket) {
    __shared__ unsigned int lh[12500];
    const int b = blockIdx.x, t = threadIdx.x;
    for (int w = t; w < 12500; w += 512) lh[w] = 0u;
    __syncthreads();
    const int e1 = (b + 1) * EPP;
    for (int e = b * EPP + t; e < e1; e += 512) {
        int d = dst[e];
        int sh = 8 * (d & 3);
        unsigned int old = atomicAdd(&lh[d >> 2], 1u << sh);
        int lr = (int)((old >> sh) & 0xffu);
        int pos = rowptr[d] + (int)cb8[(size_t)b * 50000 + d] + lr;
        bucket[pos] = make_int2(src[e], __float_as_int(ew[e]));
    }
}

// ---- degsum: segmented sum of ew over each node's CSR segment -> dinv ----
__global__ __launch_bounds__(256) void k_degsum(const int* __restrict__ rowptr,
                                                const int2* __restrict__ bucket,
                                                float* __restrict__ dinv) {
    int n = blockIdx.x * 256 + threadIdx.x;
    if (n < NN) {
        float s = 0.f;
        const int e1 = rowptr[n + 1];
        for (int e = rowptr[n]; e < e1; e++) s += __int_as_float(bucket[e].y);
        dinv[n] = rsqrtf(s + 1.0f);
    }
}

// ---- MFMA GEMM (bf16 in, bf16 out), async global_load_lds staging ----
// LDS linear; source column pre-swizzled slot^=(row&7) (both-sides rule #21).
__global__ __launch_bounds__(256, 3) void k_gemm(const unsigned short* __restrict__ Xin,
                                                 const unsigned short* __restrict__ Wt,
                                                 unsigned short* __restrict__ Y,
                                                 int nrows) {
    __shared__ char smem[49152];
    const int tid = threadIdx.x;
    const int lane = tid & 63, w = tid >> 6;
    const int r0 = blockIdx.x * 64;
    const char* Wb = (const char*)Wt;
    const char* Xb = (const char*)Xin;

#pragma unroll
    for (int j = 0; j < 12; j++) {
        const int base = (j * 4 + w) * 64;     // chunk index of lane 0 (uniform)
        const int ci = base + lane;            // 0..3071
        char* ldst = smem + (size_t)base * 16;
        if (base < 2048) {
            int row = ci >> 4, slot = ci & 15;
            ld16(Wb + row * 256 + ((slot ^ (row & 7)) * 16), ldst);
        } else {
            int xci = ci - 2048;
            int row = xci >> 4, slot = xci & 15;
            ld16(Xb + (size_t)(r0 + row) * 256 + ((slot ^ (row & 7)) * 16), ldst);
        }
    }
    __syncthreads();

    const int wr = (w >> 1) * 32, wc = (w & 1) * 64;
    const int lr = lane & 15, lg = lane >> 4;
    f32x4 acc[2][4];
#pragma unroll
    for (int a = 0; a < 2; a++)
#pragma unroll
        for (int c = 0; c < 4; c++) acc[a][c] = (f32x4){0.f, 0.f, 0.f, 0.f};

#pragma unroll
    for (int t = 0; t < 4; t++) {
        const int kb = t * 64 + lg * 16;
        bf16x8 af[2], bf[4];
#pragma unroll
        for (int i = 0; i < 2; i++) {
            int ar = wr + i * 16 + lr;
            af[i] = *(const bf16x8*)(smem + 32768 + ar * 256 + (kb ^ ((ar & 7) << 4)));
        }
#pragma unroll
        for (int i = 0; i < 4; i++) {
            int bc = wc + i * 16 + lr;
            bf[i] = *(const bf16x8*)(smem + bc * 256 + (kb ^ ((bc & 7) << 4)));
        }
#pragma unroll
        for (int fr = 0; fr < 2; fr++)
#pragma unroll
            for (int fc = 0; fc < 4; fc++)
                acc[fr][fc] = __builtin_amdgcn_mfma_f32_16x16x32_bf16(af[fr], bf[fc], acc[fr][fc], 0, 0, 0);
    }

    __syncthreads();
#pragma unroll
    for (int fr = 0; fr < 2; fr++)
#pragma unroll
        for (int fc = 0; fc < 4; fc++)
#pragma unroll
            for (int j = 0; j < 4; j++) {
                int row = wr + fr * 16 + lg * 4 + j;
                int col = wc + fc * 16 + lr;
                *(unsigned short*)(smem + row * 272 + col * 2) = f2bf(acc[fr][fc][j]);
            }
    __syncthreads();
#pragma unroll
    for (int j = 0; j < 4; j++) {
        int ci = tid + 256 * j;
        int row = ci >> 4, slot = ci & 15;
        int grow = r0 + row;
        if (grow < nrows)
            ((uint4*)(Y + (size_t)grow * 128))[slot] = *(const uint4*)(smem + row * 272 + slot * 16);
    }
}

// ---- gather-aggregate + self-loop + bias + relu (bf16 in/out) ----
// One wave per node; 4 edge-groups x 4-deep unroll = 16 row loads in flight.
__global__ __launch_bounds__(256) void k_gather(const unsigned short* __restrict__ XW,
                                                const int* __restrict__ rowptr,
                                                const int2* __restrict__ bucket,
                                                const float* __restrict__ dinv,
                                                const float* __restrict__ b,
                                                unsigned short* __restrict__ H) {
    const int wv = threadIdx.x >> 6, lane = threadIdx.x & 63;
    const int n = blockIdx.x * 4 + wv;
    if (n >= NN) return;
    const int eg = lane >> 4;        // edge group 0..3
    const int fl = lane & 15;        // 16B feature slot
    const float di = dinv[n];
    const float sl = di * di;
    uint4 su = ((const uint4*)(XW + (size_t)n * 128))[fl];
    float acc[8];
#pragma unroll
    for (int q = 0; q < 8; q++) acc[q] = 0.f;
    const int e0 = rowptr[n], e1 = rowptr[n + 1];
    int e = e0 + eg;
    for (; e + 12 < e1; e += 16) {   // 4 edges per group per iter
        int2 p0 = bucket[e];
        int2 p1 = bucket[e + 4];
        int2 p2 = bucket[e + 8];
        int2 p3 = bucket[e + 12];
        float nm0 = dinv[p0.x] * __int_as_float(p0.y) * di;
        float nm1 = dinv[p1.x] * __int_as_float(p1.y) * di;
        float nm2 = dinv[p2.x] * __int_as_float(p2.y) * di;
        float nm3 = dinv[p3.x] * __int_as_float(p3.y) * di;
        uint4 v0 = ((const uint4*)(XW + (size_t)p0.x * 128))[fl];
        uint4 v1 = ((const uint4*)(XW + (size_t)p1.x * 128))[fl];
        uint4 v2 = ((const uint4*)(XW + (size_t)p2.x * 128))[fl];
        uint4 v3 = ((const uint4*)(XW + (size_t)p3.x * 128))[fl];
        unsigned int u0[4] = {v0.x, v0.y, v0.z, v0.w};
        unsigned int u1[4] = {v1.x, v1.y, v1.z, v1.w};
        unsigned int u2[4] = {v2.x, v2.y, v2.z, v2.w};
        unsigned int u3[4] = {v3.x, v3.y, v3.z, v3.w};
#pragma unroll
        for (int q = 0; q < 4; q++) {
            acc[2 * q]     = fmaf(__uint_as_float(u0[q] << 16), nm0, acc[2 * q]);
            acc[2 * q + 1] = fmaf(__uint_as_float(u0[q] & 0xffff0000u), nm0, acc[2 * q + 1]);
            acc[2 * q]     = fmaf(__uint_as_float(u1[q] << 16), nm1, acc[2 * q]);
            acc[2 * q + 1] = fmaf(__uint_as_float(u1[q] & 0xffff0000u), nm1, acc[2 * q + 1]);
            acc[2 * q]     = fmaf(__uint_as_float(u2[q] << 16), nm2, acc[2 * q]);
            acc[2 * q + 1] = fmaf(__uint_as_float(u2[q] & 0xffff0000u), nm2, acc[2 * q + 1]);
            acc[2 * q]     = fmaf(__uint_as_float(u3[q] << 16), nm3, acc[2 * q]);
            acc[2 * q + 1] = fmaf(__uint_as_float(u3[q] & 0xffff0000u), nm3, acc[2 * q + 1]);
        }
    }
    for (; e < e1; e += 4) {         // tail, stride 4 per group
        int2 p = bucket[e];
        float nm = dinv[p.x] * __int_as_float(p.y) * di;
        uint4 v = ((const uint4*)(XW + (size_t)p.x * 128))[fl];
        unsigned int uu[4] = {v.x, v.y, v.z, v.w};
#pragma unroll
        for (int q = 0; q < 4; q++) {
            acc[2 * q]     = fmaf(__uint_as_float(uu[q] << 16), nm, acc[2 * q]);
            acc[2 * q + 1] = fmaf(__uint_as_float(uu[q] & 0xffff0000u), nm, acc[2 * q + 1]);
        }
    }
#pragma unroll
    for (int q = 0; q < 8; q++) {
        acc[q] += __shfl_xor(acc[q], 16);
        acc[q] += __shfl_xor(acc[q], 32);
    }
    if (eg == 0) {
        unsigned int us[4] = {su.x, su.y, su.z, su.w};
        float4 b0 = ((const float4*)b)[fl * 2];
        float4 b1 = ((const float4*)b)[fl * 2 + 1];
        float bb[8] = {b0.x, b0.y, b0.z, b0.w, b1.x, b1.y, b1.z, b1.w};
        float r[8];
#pragma unroll
        for (int q = 0; q < 4; q++) {
            r[2 * q]     = fmaxf(fmaf(__uint_as_float(us[q] << 16), sl, acc[2 * q]) + bb[2 * q], 0.f);
            r[2 * q + 1] = fmaxf(fmaf(__uint_as_float(us[q] & 0xffff0000u), sl, acc[2 * q + 1]) + bb[2 * q + 1], 0.f);
        }
        uint4 o;
        o.x = (unsigned)f2bf(r[0]) | ((unsigned)f2bf(r[1]) << 16);
        o.y = (unsigned)f2bf(r[2]) | ((unsigned)f2bf(r[3]) << 16);
        o.z = (unsigned)f2bf(r[4]) | ((unsigned)f2bf(r[5]) << 16);
        o.w = (unsigned)f2bf(r[6]) | ((unsigned)f2bf(r[7]) << 16);
        ((uint4*)(H + (size_t)n * 128))[fl] = o;
    }
}

// ---- fused pooling + head: one 512-thread block per graph, no atomics ----
__global__ __launch_bounds__(512) void k_poolhead(const unsigned short* __restrict__ H,
                                                  const int* __restrict__ gstart,
                                                  const float* __restrict__ linW,
                                                  const float* __restrict__ linb,
                                                  float* __restrict__ out) {
    __shared__ float lmx[1024], lsm[1024];
    __shared__ float mxf[128], mnf[128];
    const int g = blockIdx.x, t = threadIdx.x;
    const int slice = t >> 6;
    const int fp = t & 63;
    const int n0 = gstart[g], n1 = gstart[g + 1];
    float mx0 = 0.f, mx1 = 0.f, sm0 = 0.f, sm1 = 0.f;   // h >= 0 post-relu
    for (int n = n0 + slice; n < n1; n += 8) {
        unsigned int u = *(const unsigned int*)(H + (size_t)n * 128 + fp * 2);
        float v0 = bf2f((unsigned short)(u & 0xffffu));
        float v1 = bf2f((unsigned short)(u >> 16));
        mx0 = fmaxf(mx0, v0); mx1 = fmaxf(mx1, v1);
        sm0 += v0; sm1 += v1;
    }
    lmx[slice * 128 + fp * 2] = mx0; lmx[slice * 128 + fp * 2 + 1] = mx1;
    lsm[slice * 128 + fp * 2] = sm0; lsm[slice * 128 + fp * 2 + 1] = sm1;
    __syncthreads();
    if (t < 128) {
        float m = 0.f, s = 0.f;
#pragma unroll
        for (int q = 0; q < 8; q++) {
            m = fmaxf(m, lmx[q * 128 + t]);
            s += lsm[q * 128 + t];
        }
        mxf[t] = m;
        mnf[t] = s / fmaxf((float)(n1 - n0), 1.0f);
    }
    __syncthreads();
    if (t < CC) {
        float z = linb[t];
        for (int f = 0; f < 128; f++) {
            z = fmaf(mxf[f], linW[f * CC + t], z);
            z = fmaf(mnf[f], linW[(128 + f) * CC + t], z);
        }
        float m = z;
        for (int o = 8; o >= 1; o >>= 1) m = fmaxf(m, __shfl_xor(m, o, 16));
        float ex = expf(z - m), s = ex;
        for (int o = 8; o >= 1; o >>= 1) s += __shfl_xor(s, o, 16);
        out[g * CC + t] = z - m - logf(s);
    }
}

extern "C" void kernel_launch(void* const* d_in, const int* in_sizes, int n_in,
                              void* d_out, int out_size, void* d_ws, size_t ws_size,
                              hipStream_t stream) {
    const float* x    = (const float*)d_in[0];
    const int*   ei   = (const int*)d_in[1];
    const float* ew   = (const float*)d_in[2];
    const int*   batch= (const int*)d_in[3];
    const float* W1   = (const float*)d_in[4];
    const float* b1   = (const float*)d_in[5];
    const float* W2   = (const float*)d_in[6];
    const float* b2   = (const float*)d_in[7];
    const float* linW = (const float*)d_in[8];
    const float* linb = (const float*)d_in[9];
    float* out = (float*)d_out;

    // workspace layout: 16B-aligned buffers first
    unsigned short* YB = (unsigned short*)d_ws;              // [N,128] bf16 gemm out
    unsigned short* HB = YB + (size_t)NN * 128;              // [N,128] bf16 gather out
    unsigned short* XB = HB + (size_t)NN * 128;              // [N,128] bf16 input / h2
    unsigned short* WT1 = XB + (size_t)NN * 128;             // [128*128]
    unsigned short* WT2 = WT1 + 128 * 128;                   // [128*128]
    int2*  BUCKET = (int2*)(WT2 + 128 * 128);                // [E] (src, ew)
    float* DINV   = (float*)(BUCKET + EE);                   // [N]
    int*   ROWPTR = (int*)(DINV + NN);                       // [N+1]
    int*   CNT    = ROWPTR + NN + 1;                         // [N]
    int*   GSTART = CNT + NN;                                // [G+1]
    int*   BS     = GSTART + GG + 1;                         // [NBLK]
    unsigned int* HISTW = (unsigned int*)(BS + NBLK + 1);    // [PP][12500] u8x4
    unsigned char* CB8 = (unsigned char*)(HISTW + (size_t)PP * 12500); // [PP][50000] u8

    const int* src = ei;
    const int* dst = ei + EE;

    // prep: hist | W transpose | gstart | x->bf16
    k_prep<<<PREPB, 512, 0, stream>>>(x, XB, W1, W2, WT1, WT2, batch, GSTART, dst, HISTW);

    // layer-1 GEMM (independent of CSR build)
    k_gemm<<<GEMMB, 256, 0, stream>>>(XB, WT1, YB, NN);

    // CSR build — no global atomics anywhere
    k_scanA<<<NBLK, 256, 0, stream>>>((const unsigned char*)HISTW, CB8, CNT, BS);
    k_scanBC<<<NBLK, 256, 0, stream>>>(BS, CNT, ROWPTR);
    k_fill<<<PP, 512, 0, stream>>>(src, dst, ew, ROWPTR, CB8, BUCKET);
    k_degsum<<<NBLK, 256, 0, stream>>>(ROWPTR, BUCKET, DINV);

    // layer 1 aggregate
    k_gather<<<(NN + 3) / 4, 256, 0, stream>>>(YB, ROWPTR, BUCKET, DINV, b1, HB);

    // layer 2
    k_gemm<<<GEMMB, 256, 0, stream>>>(HB, WT2, YB, NN);
    k_gather<<<(NN + 3) / 4, 256, 0, stream>>>(YB, ROWPTR, BUCKET, DINV, b2, XB);

    // pooling + head (one block per graph)
    k_poolhead<<<GG, 512, 0, stream>>>(XB, GSTART, linW, linb, out);
}

// Round 20
// 139.655 us; speedup vs baseline: 1.6676x; 1.0461x over previous
//
#include <hip/hip_runtime.h>
#include <hip/hip_bf16.h>

#define NN 50000
#define EE 600000
#define FH 128
#define GG 128
#define CC 16
#define NBLK ((NN + 255) / 256)   // 196 node blocks
#define GEMMB 782                 // 64-row gemm tiles
#define PP 192                    // edge chunks (hist/fill blocks)
#define EPP 3125                  // edges per chunk (192*3125 == 600000)

typedef __attribute__((ext_vector_type(8))) short bf16x8;
typedef __attribute__((ext_vector_type(4))) float f32x4;
typedef __attribute__((ext_vector_type(2))) float f32x2;

static __device__ __forceinline__ unsigned short f2bf(float f) {
    union { float f; unsigned int u; } v; v.f = f;
    unsigned int r = v.u + 0x7fffu + ((v.u >> 16) & 1u);   // RNE
    return (unsigned short)(r >> 16);
}
static __device__ __forceinline__ float bf2f(unsigned short h) {
    union { unsigned int u; float f; } v; v.u = ((unsigned int)h) << 16;
    return v.f;
}
// async global->LDS, 16B per lane; lds base must be wave-uniform
static __device__ __forceinline__ void ld16(const void* g, void* l) {
    __builtin_amdgcn_global_load_lds((const __attribute__((address_space(1))) void*)g,
                                     (__attribute__((address_space(3))) void*)l, 16, 0, 0);
}
// fp8(e4m3) row fragment (8 features in a uint2) -> 8 fp32 FMAs into acc
static __device__ __forceinline__ void acc8(float* acc, uint2 v, float nm) {
    f32x2 a0 = __builtin_amdgcn_cvt_pk_f32_fp8(v.x, false);
    f32x2 a1 = __builtin_amdgcn_cvt_pk_f32_fp8(v.x, true);
    f32x2 a2 = __builtin_amdgcn_cvt_pk_f32_fp8(v.y, false);
    f32x2 a3 = __builtin_amdgcn_cvt_pk_f32_fp8(v.y, true);
    acc[0] = fmaf(a0.x, nm, acc[0]);
    acc[1] = fmaf(a0.y, nm, acc[1]);
    acc[2] = fmaf(a1.x, nm, acc[2]);
    acc[3] = fmaf(a1.y, nm, acc[3]);
    acc[4] = fmaf(a2.x, nm, acc[4]);
    acc[5] = fmaf(a2.y, nm, acc[5]);
    acc[6] = fmaf(a3.x, nm, acc[6]);
    acc[7] = fmaf(a3.y, nm, acc[7]);
}

// ---- prep (512 thr): W transpose | gstart | x->bf16 | per-chunk dst hist ----
__global__ __launch_bounds__(512) void k_prep(const float* __restrict__ x,
                                              unsigned short* __restrict__ XB,
                                              const float* __restrict__ W1,
                                              const float* __restrict__ W2,
                                              unsigned short* __restrict__ WT1,
                                              unsigned short* __restrict__ WT2,
                                              const int* __restrict__ batch,
                                              int* __restrict__ gstart,
                                              const int* __restrict__ dst,
                                              unsigned int* __restrict__ histw) {
    __shared__ unsigned int lh[12500];         // only hist blocks use it
    const int b = blockIdx.x, t = threadIdx.x;
    if (b < PP) {                              // hist chunk b
        for (int w = t; w < 12500; w += 512) lh[w] = 0u;
        __syncthreads();
        const int e1 = (b + 1) * EPP;
        for (int e = b * EPP + t; e < e1; e += 512) {
            int d = dst[e];
            atomicAdd(&lh[d >> 2], 1u << (8 * (d & 3)));
        }
        __syncthreads();
        for (int w = t; w < 12500; w += 512) histw[(size_t)b * 12500 + w] = lh[w];
    } else if (b < PP + 64) {
        int o = (b - PP) * 512 + t;            // 0..32767
        const float* W = (o < 16384) ? W1 : W2;
        unsigned short* WT = (o < 16384) ? WT1 : WT2;
        int oo = o & 16383;
        int c = oo >> 7, k = oo & 127;
        WT[oo] = f2bf(W[k * 128 + c]);
    } else if (b == PP + 64) {
        if (t <= GG) {
            int lo = 0, hi = NN;
            while (lo < hi) {
                int mid = (lo + hi) >> 1;
                if (batch[mid] < t) lo = mid + 1; else hi = mid;
            }
            gstart[t] = lo;
        }
    } else {
        int o = (b - PP - 65) * 512 + t;       // 8 floats each, guard 800000
        if (o < 800000) {
            const float4* xp = (const float4*)x + (size_t)o * 2;
            float4 f0 = xp[0], f1 = xp[1];
            uint4 v;
            v.x = (unsigned)f2bf(f0.x) | ((unsigned)f2bf(f0.y) << 16);
            v.y = (unsigned)f2bf(f0.z) | ((unsigned)f2bf(f0.w) << 16);
            v.z = (unsigned)f2bf(f1.x) | ((unsigned)f2bf(f1.y) << 16);
            v.w = (unsigned)f2bf(f1.z) | ((unsigned)f2bf(f1.w) << 16);
            ((uint4*)XB)[o] = v;
        }
    }
}
#define PREPB (PP + 65 + 1563)   // 192 hist + 64 W + 1 gstart + 1563 conv

// ---- scanA: per-node total count + per-chunk u8 cursor bases + block sums ----
__global__ __launch_bounds__(256) void k_scanA(const unsigned char* __restrict__ hist8,
                                               unsigned char* __restrict__ cb8,
                                               int* __restrict__ cnt,
                                               int* __restrict__ bs) {
    int i = blockIdx.x * 256 + threadIdx.x;
    int run = 0;
    if (i < NN) {
        for (int p = 0; p < PP; p += 32) {
            unsigned char hh[32];
#pragma unroll
            for (int q = 0; q < 32; q++) hh[q] = hist8[(size_t)(p + q) * 50000 + i];
#pragma unroll
            for (int q = 0; q < 32; q++) {
                cb8[(size_t)(p + q) * 50000 + i] = (unsigned char)run;
                run += hh[q];
            }
        }
        cnt[i] = run;
    }
    int v = run;
#pragma unroll
    for (int o = 32; o >= 1; o >>= 1) v += __shfl_down(v, o, 64);
    __shared__ int ws[4];
    if ((threadIdx.x & 63) == 0) ws[threadIdx.x >> 6] = v;
    __syncthreads();
    if (threadIdx.x == 0) bs[blockIdx.x] = ws[0] + ws[1] + ws[2] + ws[3];
}

// ---- scanBC: redundant block-sum scan in LDS + per-chunk scan -> rowptr ----
__global__ __launch_bounds__(256) void k_scanBC(const int* __restrict__ bs,
                                                const int* __restrict__ cnt,
                                                int* __restrict__ rowptr) {
    __shared__ int sb[256];
    __shared__ int sc[256];
    const int t = threadIdx.x, b = blockIdx.x;
    int vb = (t < NBLK) ? bs[t] : 0;
    sb[t] = vb;
    __syncthreads();
    for (int off = 1; off < 256; off <<= 1) {
        int add = (t >= off) ? sb[t - off] : 0;
        __syncthreads();
        sb[t] += add;
        __syncthreads();
    }
    const int boff = (b > 0) ? sb[b - 1] : 0;
    const int i = b * 256 + t;
    int v = (i < NN) ? cnt[i] : 0;
    sc[t] = v;
    __syncthreads();
    for (int off = 1; off < 256; off <<= 1) {
        int add = (t >= off) ? sc[t - off] : 0;
        __syncthreads();
        sc[t] += add;
        __syncthreads();
    }
    int excl = sc[t] - v + boff;
    if (i < NN) rowptr[i] = excl;
    if (i == 0) rowptr[NN] = EE;
}

// ---- fill: replay chunk with LDS returning atomics -> bucket (src, ew) ----
__global__ __launch_bounds__(512) void k_fill(const int* __restrict__ src,
                                              const int* __restrict__ dst,
                                              const float* __restrict__ ew,
                                              const int* __restrict__ rowptr,
                                              const unsigned char* __restrict__ cb8,
                                              int2* __restrict__ bucket) {
    __shared__ unsigned int lh[12500];
    const int b = blockIdx.x, t = threadIdx.x;
    for (int w = t; w < 12500; w += 512) lh[w] = 0u;
    __syncthreads();
    const int e1 = (b + 1) * EPP;
    for (int e = b * EPP + t; e < e1; e += 512) {
        int d = dst[e];
        int sh = 8 * (d & 3);
        unsigned int old = atomicAdd(&lh[d >> 2], 1u << sh);
        int lr = (int)((old >> sh) & 0xffu);
        int pos = rowptr[d] + (int)cb8[(size_t)b * 50000 + d] + lr;
        bucket[pos] = make_int2(src[e], __float_as_int(ew[e]));
    }
}

// ---- degsum: segmented sum of ew over each node's CSR segment -> dinv ----
__global__ __launch_bounds__(256) void k_degsum(const int* __restrict__ rowptr,
                                                const int2* __restrict__ bucket,
                                                float* __restrict__ dinv) {
    int n = blockIdx.x * 256 + threadIdx.x;
    if (n < NN) {
        float s = 0.f;
        const int e1 = rowptr[n + 1];
        for (int e = rowptr[n]; e < e1; e++) s += __int_as_float(bucket[e].y);
        dinv[n] = rsqrtf(s + 1.0f);
    }
}

// ---- MFMA GEMM (bf16 in, fp8-e4m3 out), async global_load_lds staging ----
// LDS linear; source column pre-swizzled slot^=(row&7) (both-sides rule #21).
// fp8 output halves the gather kernels' random-row traffic.
__global__ __launch_bounds__(256, 3) void k_gemm(const unsigned short* __restrict__ Xin,
                                                 const unsigned short* __restrict__ Wt,
                                                 unsigned char* __restrict__ Y,
                                                 int nrows) {
    __shared__ char smem[49152];
    const int tid = threadIdx.x;
    const int lane = tid & 63, w = tid >> 6;
    const int r0 = blockIdx.x * 64;
    const char* Wb = (const char*)Wt;
    const char* Xb = (const char*)Xin;

#pragma unroll
    for (int j = 0; j < 12; j++) {
        const int base = (j * 4 + w) * 64;     // chunk index of lane 0 (uniform)
        const int ci = base + lane;            // 0..3071
        char* ldst = smem + (size_t)base * 16;
        if (base < 2048) {
            int row = ci >> 4, slot = ci & 15;
            ld16(Wb + row * 256 + ((slot ^ (row & 7)) * 16), ldst);
        } else {
            int xci = ci - 2048;
            int row = xci >> 4, slot = xci & 15;
            ld16(Xb + (size_t)(r0 + row) * 256 + ((slot ^ (row & 7)) * 16), ldst);
        }
    }
    __syncthreads();

    const int wr = (w >> 1) * 32, wc = (w & 1) * 64;
    const int lr = lane & 15, lg = lane >> 4;
    f32x4 acc[2][4];
#pragma unroll
    for (int a = 0; a < 2; a++)
#pragma unroll
        for (int c = 0; c < 4; c++) acc[a][c] = (f32x4){0.f, 0.f, 0.f, 0.f};

#pragma unroll
    for (int t = 0; t < 4; t++) {
        const int kb = t * 64 + lg * 16;
        bf16x8 af[2], bf[4];
#pragma unroll
        for (int i = 0; i < 2; i++) {
            int ar = wr + i * 16 + lr;
            af[i] = *(const bf16x8*)(smem + 32768 + ar * 256 + (kb ^ ((ar & 7) << 4)));
        }
#pragma unroll
        for (int i = 0; i < 4; i++) {
            int bc = wc + i * 16 + lr;
            bf[i] = *(const bf16x8*)(smem + bc * 256 + (kb ^ ((bc & 7) << 4)));
        }
#pragma unroll
        for (int fr = 0; fr < 2; fr++)
#pragma unroll
            for (int fc = 0; fc < 4; fc++)
                acc[fr][fc] = __builtin_amdgcn_mfma_f32_16x16x32_bf16(af[fr], bf[fc], acc[fr][fc], 0, 0, 0);
    }

    // epilogue: fp8 bytes through LDS bounce (pitch 144B) -> coalesced stores
    __syncthreads();
#pragma unroll
    for (int fr = 0; fr < 2; fr++)
#pragma unroll
        for (int fc = 0; fc < 4; fc++)
#pragma unroll
            for (int j = 0; j < 4; j++) {
                int row = wr + fr * 16 + lg * 4 + j;
                int col = wc + fc * 16 + lr;
                int pk = __builtin_amdgcn_cvt_pk_fp8_f32(acc[fr][fc][j], 0.f, 0, false);
                *(unsigned char*)(smem + row * 144 + col) = (unsigned char)(pk & 0xff);
            }
    __syncthreads();
#pragma unroll
    for (int j = 0; j < 2; j++) {
        int ci = tid + 256 * j;                // 0..511 chunks (64 rows x 8)
        int row = ci >> 3, slot = ci & 7;
        int grow = r0 + row;
        if (grow < nrows)
            ((uint4*)(Y + (size_t)grow * 128))[slot] = *(const uint4*)(smem + row * 144 + slot * 16);
    }
}

// ---- gather-aggregate + self-loop + bias + relu (fp8 in, bf16 out) ----
// One wave per node; 4 edge-groups x 4-deep unroll = 16 row loads in flight.
// Rows are fp8 e4m3 (128B): halves the random-line traffic vs bf16.
__global__ __launch_bounds__(256) void k_gather(const unsigned char* __restrict__ XW8,
                                                const int* __restrict__ rowptr,
                                                const int2* __restrict__ bucket,
                                                const float* __restrict__ dinv,
                                                const float* __restrict__ b,
                                                unsigned short* __restrict__ H) {
    const int wv = threadIdx.x >> 6, lane = threadIdx.x & 63;
    const int n = blockIdx.x * 4 + wv;
    if (n >= NN) return;
    const int eg = lane >> 4;        // edge group 0..3
    const int fl = lane & 15;        // 8B feature slot -> features 8*fl..8*fl+7
    const float di = dinv[n];
    const float sl = di * di;
    uint2 su = ((const uint2*)(XW8 + (size_t)n * 128))[fl];
    float acc[8];
#pragma unroll
    for (int q = 0; q < 8; q++) acc[q] = 0.f;
    const int e0 = rowptr[n], e1 = rowptr[n + 1];
    int e = e0 + eg;
    for (; e + 12 < e1; e += 16) {   // 4 edges per group per iter
        int2 p0 = bucket[e];
        int2 p1 = bucket[e + 4];
        int2 p2 = bucket[e + 8];
        int2 p3 = bucket[e + 12];
        float nm0 = dinv[p0.x] * __int_as_float(p0.y) * di;
        float nm1 = dinv[p1.x] * __int_as_float(p1.y) * di;
        float nm2 = dinv[p2.x] * __int_as_float(p2.y) * di;
        float nm3 = dinv[p3.x] * __int_as_float(p3.y) * di;
        uint2 v0 = ((const uint2*)(XW8 + (size_t)p0.x * 128))[fl];
        uint2 v1 = ((const uint2*)(XW8 + (size_t)p1.x * 128))[fl];
        uint2 v2 = ((const uint2*)(XW8 + (size_t)p2.x * 128))[fl];
        uint2 v3 = ((const uint2*)(XW8 + (size_t)p3.x * 128))[fl];
        acc8(acc, v0, nm0);
        acc8(acc, v1, nm1);
        acc8(acc, v2, nm2);
        acc8(acc, v3, nm3);
    }
    for (; e < e1; e += 4) {         // tail, stride 4 per group
        int2 p = bucket[e];
        float nm = dinv[p.x] * __int_as_float(p.y) * di;
        uint2 v = ((const uint2*)(XW8 + (size_t)p.x * 128))[fl];
        acc8(acc, v, nm);
    }
#pragma unroll
    for (int q = 0; q < 8; q++) {
        acc[q] += __shfl_xor(acc[q], 16);
        acc[q] += __shfl_xor(acc[q], 32);
    }
    if (eg == 0) {
        f32x2 s0 = __builtin_amdgcn_cvt_pk_f32_fp8(su.x, false);
        f32x2 s1 = __builtin_amdgcn_cvt_pk_f32_fp8(su.x, true);
        f32x2 s2 = __builtin_amdgcn_cvt_pk_f32_fp8(su.y, false);
        f32x2 s3 = __builtin_amdgcn_cvt_pk_f32_fp8(su.y, true);
        float sv[8] = {s0.x, s0.y, s1.x, s1.y, s2.x, s2.y, s3.x, s3.y};
        float4 b0 = ((const float4*)b)[fl * 2];
        float4 b1 = ((const float4*)b)[fl * 2 + 1];
        float bb[8] = {b0.x, b0.y, b0.z, b0.w, b1.x, b1.y, b1.z, b1.w};
        float r[8];
#pragma unroll
        for (int q = 0; q < 8; q++)
            r[q] = fmaxf(fmaf(sv[q], sl, acc[q]) + bb[q], 0.f);
        uint4 o;
        o.x = (unsigned)f2bf(r[0]) | ((unsigned)f2bf(r[1]) << 16);
        o.y = (unsigned)f2bf(r[2]) | ((unsigned)f2bf(r[3]) << 16);
        o.z = (unsigned)f2bf(r[4]) | ((unsigned)f2bf(r[5]) << 16);
        o.w = (unsigned)f2bf(r[6]) | ((unsigned)f2bf(r[7]) << 16);
        ((uint4*)(H + (size_t)n * 128))[fl] = o;
    }
}

// ---- fused pooling + head: one 512-thread block per graph, no atomics ----
__global__ __launch_bounds__(512) void k_poolhead(const unsigned short* __restrict__ H,
                                                  const int* __restrict__ gstart,
                                                  const float* __restrict__ linW,
                                                  const float* __restrict__ linb,
                                                  float* __restrict__ out) {
    __shared__ float lmx[1024], lsm[1024];
    __shared__ float mxf[128], mnf[128];
    const int g = blockIdx.x, t = threadIdx.x;
    const int slice = t >> 6;
    const int fp = t & 63;
    const int n0 = gstart[g], n1 = gstart[g + 1];
    float mx0 = 0.f, mx1 = 0.f, sm0 = 0.f, sm1 = 0.f;   // h >= 0 post-relu
    for (int n = n0 + slice; n < n1; n += 8) {
        unsigned int u = *(const unsigned int*)(H + (size_t)n * 128 + fp * 2);
        float v0 = bf2f((unsigned short)(u & 0xffffu));
        float v1 = bf2f((unsigned short)(u >> 16));
        mx0 = fmaxf(mx0, v0); mx1 = fmaxf(mx1, v1);
        sm0 += v0; sm1 += v1;
    }
    lmx[slice * 128 + fp * 2] = mx0; lmx[slice * 128 + fp * 2 + 1] = mx1;
    lsm[slice * 128 + fp * 2] = sm0; lsm[slice * 128 + fp * 2 + 1] = sm1;
    __syncthreads();
    if (t < 128) {
        float m = 0.f, s = 0.f;
#pragma unroll
        for (int q = 0; q < 8; q++) {
            m = fmaxf(m, lmx[q * 128 + t]);
            s += lsm[q * 128 + t];
        }
        mxf[t] = m;
        mnf[t] = s / fmaxf((float)(n1 - n0), 1.0f);
    }
    __syncthreads();
    if (t < CC) {
        float z = linb[t];
        for (int f = 0; f < 128; f++) {
            z = fmaf(mxf[f], linW[f * CC + t], z);
            z = fmaf(mnf[f], linW[(128 + f) * CC + t], z);
        }
        float m = z;
        for (int o = 8; o >= 1; o >>= 1) m = fmaxf(m, __shfl_xor(m, o, 16));
        float ex = expf(z - m), s = ex;
        for (int o = 8; o >= 1; o >>= 1) s += __shfl_xor(s, o, 16);
        out[g * CC + t] = z - m - logf(s);
    }
}

extern "C" void kernel_launch(void* const* d_in, const int* in_sizes, int n_in,
                              void* d_out, int out_size, void* d_ws, size_t ws_size,
                              hipStream_t stream) {
    const float* x    = (const float*)d_in[0];
    const int*   ei   = (const int*)d_in[1];
    const float* ew   = (const float*)d_in[2];
    const int*   batch= (const int*)d_in[3];
    const float* W1   = (const float*)d_in[4];
    const float* b1   = (const float*)d_in[5];
    const float* W2   = (const float*)d_in[6];
    const float* b2   = (const float*)d_in[7];
    const float* linW = (const float*)d_in[8];
    const float* linb = (const float*)d_in[9];
    float* out = (float*)d_out;

    // workspace layout: 16B-aligned buffers first
    unsigned char*  Y8 = (unsigned char*)d_ws;               // [N,128] fp8 gemm out
    unsigned short* H  = (unsigned short*)(Y8 + (size_t)NN * 128); // [N,128] bf16 h1
    unsigned short* XB = H + (size_t)NN * 128;               // [N,128] bf16 input / h2
    unsigned short* WT1 = XB + (size_t)NN * 128;             // [128*128]
    unsigned short* WT2 = WT1 + 128 * 128;                   // [128*128]
    int2*  BUCKET = (int2*)(WT2 + 128 * 128);                // [E] (src, ew)
    float* DINV   = (float*)(BUCKET + EE);                   // [N]
    int*   ROWPTR = (int*)(DINV + NN);                       // [N+1]
    int*   CNT    = ROWPTR + NN + 1;                         // [N]
    int*   GSTART = CNT + NN;                                // [G+1]
    int*   BS     = GSTART + GG + 1;                         // [NBLK]
    unsigned int* HISTW = (unsigned int*)(BS + NBLK + 1);    // [PP][12500] u8x4
    unsigned char* CB8 = (unsigned char*)(HISTW + (size_t)PP * 12500); // [PP][50000] u8

    const int* src = ei;
    const int* dst = ei + EE;

    // prep: hist | W transpose | gstart | x->bf16
    k_prep<<<PREPB, 512, 0, stream>>>(x, XB, W1, W2, WT1, WT2, batch, GSTART, dst, HISTW);

    // layer-1 GEMM (independent of CSR build), fp8 out
    k_gemm<<<GEMMB, 256, 0, stream>>>(XB, WT1, Y8, NN);

    // CSR build — no global atomics anywhere
    k_scanA<<<NBLK, 256, 0, stream>>>((const unsigned char*)HISTW, CB8, CNT, BS);
    k_scanBC<<<NBLK, 256, 0, stream>>>(BS, CNT, ROWPTR);
    k_fill<<<PP, 512, 0, stream>>>(src, dst, ew, ROWPTR, CB8, BUCKET);
    k_degsum<<<NBLK, 256, 0, stream>>>(ROWPTR, BUCKET, DINV);

    // layer 1 aggregate (fp8 rows -> bf16 h1)
    k_gather<<<(NN + 3) / 4, 256, 0, stream>>>(Y8, ROWPTR, BUCKET, DINV, b1, H);

    // layer 2
    k_gemm<<<GEMMB, 256, 0, stream>>>(H, WT2, Y8, NN);
    k_gather<<<(NN + 3) / 4, 256, 0, stream>>>(Y8, ROWPTR, BUCKET, DINV, b2, XB);

    // pooling + head (one block per graph)
    k_poolhead<<<GG, 512, 0, stream>>>(XB, GSTART, linW, linb, out);
}